// Round 3
// baseline (134.860 us; speedup 1.0000x reference)
//
#include <hip/hip_runtime.h>

#define LSEQ 32768
#define HDIM 256
#define PDIM 256
#define CHUNK 64
#define NCHUNK 512   // LSEQ / CHUNK

typedef __attribute__((ext_vector_type(8))) short short8;
typedef __attribute__((ext_vector_type(4))) float f32x4;

static __device__ __forceinline__ unsigned short f2bf(float f) {
    unsigned int u = __float_as_uint(f);
    return (unsigned short)((u + 0x7FFFu + ((u >> 16) & 1u)) >> 16);
}
static __device__ __forceinline__ float bf2f(unsigned int lo16) {
    return __uint_as_float(lo16 << 16);
}

// ---------------------------------------------------------------------------
// prep1: discretization + power table Abar^k (k=0..CHUNK), fp32
// ---------------------------------------------------------------------------
__global__ void s5_prep1(const float* __restrict__ Lambda,
                         const float* __restrict__ log_step,
                         float* __restrict__ Abar,   // (P,2)
                         float* __restrict__ g,      // (P,2)
                         float* __restrict__ powt)   // (CHUNK+1, 512)
{
    int p = threadIdx.x;
    float lr = Lambda[2 * p], li = Lambda[2 * p + 1];
    float step = expf(log_step[p]);
    float s2 = 0.5f * step;
    float dr = 1.0f - s2 * lr;
    float di = -s2 * li;
    float inv = 1.0f / (dr * dr + di * di);
    float blr = dr * inv, bli = -di * inv;
    float nr = 1.0f + s2 * lr, ni = s2 * li;
    float ar = blr * nr - bli * ni;
    float ai = blr * ni + bli * nr;
    Abar[2 * p] = ar; Abar[2 * p + 1] = ai;
    g[2 * p] = blr * step; g[2 * p + 1] = bli * step;

    float pr = 1.0f, pi = 0.0f;
    powt[2 * p] = 1.0f; powt[2 * p + 1] = 0.0f;
    for (int k = 1; k <= CHUNK; ++k) {
        float t = pr * ar - pi * ai;
        pi = pr * ai + pi * ar;
        pr = t;
        powt[k * 512 + 2 * p] = pr;
        powt[k * 512 + 2 * p + 1] = pi;
    }
}

// ---------------------------------------------------------------------------
// prep2: bf16 transposed weights (N-major, K contiguous)
//   W1T (2P x H): W1T[2p+ri][h] = (g_p * B~[p][h]) re/im
//   W2T (H x 2P): W2T[h][2p] = C_re[h][p], W2T[h][2p+1] = -C_im[h][p]
// ---------------------------------------------------------------------------
__global__ void s5_prep2(const float* __restrict__ B,
                         const float* __restrict__ C,
                         const float* __restrict__ g,
                         short* __restrict__ W1T,
                         short* __restrict__ W2T)
{
    int b = blockIdx.x, t = threadIdx.x;
    {   // W1T: p = b, h = t
        int p = b, h = t;
        float gr = g[2 * p], gi = g[2 * p + 1];
        float br = B[(size_t)(p * HDIM + h) * 2];
        float bi = B[(size_t)(p * HDIM + h) * 2 + 1];
        W1T[(size_t)(2 * p) * 256 + h]     = (short)f2bf(gr * br - gi * bi);
        W1T[(size_t)(2 * p + 1) * 256 + h] = (short)f2bf(gr * bi + gi * br);
    }
    {   // W2T: h = b, p = t
        int h = b, p = t;
        float cr = C[(size_t)(h * PDIM + p) * 2];
        float ci = C[(size_t)(h * PDIM + p) * 2 + 1];
        W2T[(size_t)h * 512 + 2 * p]     = (short)f2bf(cr);
        W2T[(size_t)h * 512 + 2 * p + 1] = (short)f2bf(-ci);
    }
}

// ---------------------------------------------------------------------------
// kA: per chunk, GEMM1 (bf16 MFMA) -> Bu in LDS (fp32, per N-half) ->
//     local_end[c][p] = sum_k Abar^{63-k} Bu[k][p]  (parallel weighted sum)
// grid 512 x 512 threads (8 waves: 2m x 4n)
// ---------------------------------------------------------------------------
__global__ __launch_bounds__(512, 2) void s5_localend(
    const float* __restrict__ U,
    const short* __restrict__ W1T,
    const float* __restrict__ Abar,
    const float* __restrict__ powt,
    float* __restrict__ local_end)
{
    __shared__ short A_u[64 * 264];   // u tile bf16, pad 256->264
    __shared__ float BuF[64 * 260];   // one N-half of Bu, fp32, pad 256->260
    __shared__ short Bst[256 * 40];   // W staging [256 n][32 k], pad 32->40
    __shared__ float2 pbuf[4][128];   // strip partials

    const int tid = threadIdx.x;
    const int lane = tid & 63, w = tid >> 6;
    const int wm = w >> 2, wn = w & 3;
    const int c = blockIdx.x;
    const int m0 = c * CHUNK;

    // stage u tile -> bf16
    #pragma unroll
    for (int i = 0; i < 4; ++i) {
        int lin = tid + i * 512;
        int row = lin >> 5, off = (lin & 31) << 3;
        const float4* up = (const float4*)&U[(size_t)(m0 + row) * 256 + off];
        float4 v0 = up[0], v1 = up[1];
        short8 s;
        s[0] = (short)f2bf(v0.x); s[1] = (short)f2bf(v0.y);
        s[2] = (short)f2bf(v0.z); s[3] = (short)f2bf(v0.w);
        s[4] = (short)f2bf(v1.x); s[5] = (short)f2bf(v1.y);
        s[6] = (short)f2bf(v1.z); s[7] = (short)f2bf(v1.w);
        *(short8*)&A_u[row * 264 + off] = s;
    }

    for (int half = 0; half < 2; ++half) {
        f32x4 acc1[2][4] = {};
        for (int s = 0; s < 8; ++s) {
            int k0 = s * 32;
            #pragma unroll
            for (int i = 0; i < 2; ++i) {
                int lin = tid + i * 512;
                int n = lin >> 2, kc = (lin & 3) << 3;
                *(short8*)&Bst[n * 40 + kc] =
                    *(const short8*)&W1T[(size_t)(half * 256 + n) * 256 + k0 + kc];
            }
            __syncthreads();
            short8 af[2], bf[4];
            #pragma unroll
            for (int mi = 0; mi < 2; ++mi)
                af[mi] = *(const short8*)&A_u[(wm * 32 + mi * 16 + (lane & 15)) * 264 + k0 + ((lane >> 4) << 3)];
            #pragma unroll
            for (int ni = 0; ni < 4; ++ni)
                bf[ni] = *(const short8*)&Bst[(wn * 64 + ni * 16 + (lane & 15)) * 40 + ((lane >> 4) << 3)];
            #pragma unroll
            for (int mi = 0; mi < 2; ++mi)
                #pragma unroll
                for (int ni = 0; ni < 4; ++ni)
                    acc1[mi][ni] = __builtin_amdgcn_mfma_f32_16x16x32_bf16(af[mi], bf[ni], acc1[mi][ni], 0, 0, 0);
            __syncthreads();
        }
        // acc1 -> BuF (fp32)
        #pragma unroll
        for (int mi = 0; mi < 2; ++mi) {
            int rb = wm * 32 + mi * 16 + ((lane >> 4) << 2);
            #pragma unroll
            for (int ni = 0; ni < 4; ++ni) {
                int col = wn * 64 + ni * 16 + (lane & 15);
                #pragma unroll
                for (int r = 0; r < 4; ++r)
                    BuF[(rb + r) * 260 + col] = acc1[mi][ni][r];
            }
        }
        __syncthreads();

        // weighted sum: ch = tid&127, strip = tid>>7 covers rows [16s,16s+16)
        {
            int ch = tid & 127, strip = tid >> 7;
            int pgl = half * 128 + ch;
            float2 a = ((const float2*)Abar)[pgl];
            float2 wgt = ((const float2*)powt)[(size_t)(48 - 16 * strip) * 256 + pgl];
            float sr = 0.0f, si = 0.0f;
            #pragma unroll
            for (int j = 0; j < 16; ++j) {
                int r = 16 * strip + 15 - j;
                float2 bu = *(const float2*)&BuF[r * 260 + 2 * ch];
                sr = fmaf(wgt.x, bu.x, fmaf(-wgt.y, bu.y, sr));
                si = fmaf(wgt.x, bu.y, fmaf(wgt.y, bu.x, si));
                float t = wgt.x * a.x - wgt.y * a.y;
                wgt.y = wgt.x * a.y + wgt.y * a.x;
                wgt.x = t;
            }
            pbuf[strip][ch] = make_float2(sr, si);
        }
        __syncthreads();
        if (tid < 128) {
            int ch = tid;
            float2 s0 = pbuf[0][ch], s1 = pbuf[1][ch], s2 = pbuf[2][ch], s3 = pbuf[3][ch];
            float2 le = make_float2(s0.x + s1.x + s2.x + s3.x, s0.y + s1.y + s2.y + s3.y);
            ((float2*)local_end)[(size_t)c * 256 + half * 128 + ch] = le;
        }
        __syncthreads();
    }
}

// ---------------------------------------------------------------------------
// kB: sequential carry scan over 512 chunks; writes carry_in per chunk and
// final state to d_out tail.
// ---------------------------------------------------------------------------
__global__ void s5_scan2(const float* __restrict__ local_end,
                         float* __restrict__ carry,
                         const float* __restrict__ powt,
                         float* __restrict__ out_state)
{
    int p = threadIdx.x;
    float2 A = ((const float2*)powt)[CHUNK * 256 + p];   // Abar^64
    float cr = 0.0f, ci = 0.0f;
    for (int cb = 0; cb < NCHUNK; cb += 16) {
        float2 e[16];
        #pragma unroll
        for (int j = 0; j < 16; ++j)
            e[j] = ((const float2*)local_end)[(size_t)(cb + j) * 256 + p];
        #pragma unroll
        for (int j = 0; j < 16; ++j) {
            ((float2*)carry)[(size_t)(cb + j) * 256 + p] = make_float2(cr, ci);
            float nr = fmaf(A.x, cr, fmaf(-A.y, ci, e[j].x));
            float ni = fmaf(A.x, ci, fmaf(A.y, cr, e[j].y));
            cr = nr; ci = ni;
        }
    }
    out_state[2 * p] = cr;
    out_state[2 * p + 1] = ci;
}

// ---------------------------------------------------------------------------
// kC: per chunk: GEMM1 -> Bu (LDS fp32, per N-half) -> exact scan with carry
// init -> xs bf16 (LDS) -> GEMM2 K-half accumulate -> +D*u -> out.
// xs never goes to HBM. grid 512 x 512 threads.
// ---------------------------------------------------------------------------
__global__ __launch_bounds__(512, 2) void s5_fused(
    const float* __restrict__ U,
    const short* __restrict__ W1T,
    const short* __restrict__ W2T,
    const float* __restrict__ Abar,
    const float* __restrict__ carry,
    const float* __restrict__ Dv,
    float* __restrict__ Out)
{
    __shared__ short A_u[64 * 264];    // 33792 B
    __shared__ float BuF[64 * 260];    // 66560 B
    __shared__ short Bst[256 * 40];    // 20480 B
    __shared__ short XSh[64 * 264];    // 33792 B (one K-half of xs, bf16)
    __shared__ float2 sEnd[128];       // 1024 B

    const int tid = threadIdx.x;
    const int lane = tid & 63, w = tid >> 6;
    const int wm = w >> 2, wn = w & 3;
    const int c = blockIdx.x;
    const int m0 = c * CHUNK;

    // stage u tile -> bf16
    #pragma unroll
    for (int i = 0; i < 4; ++i) {
        int lin = tid + i * 512;
        int row = lin >> 5, off = (lin & 31) << 3;
        const float4* up = (const float4*)&U[(size_t)(m0 + row) * 256 + off];
        float4 v0 = up[0], v1 = up[1];
        short8 s;
        s[0] = (short)f2bf(v0.x); s[1] = (short)f2bf(v0.y);
        s[2] = (short)f2bf(v0.z); s[3] = (short)f2bf(v0.w);
        s[4] = (short)f2bf(v1.x); s[5] = (short)f2bf(v1.y);
        s[6] = (short)f2bf(v1.z); s[7] = (short)f2bf(v1.w);
        *(short8*)&A_u[row * 264 + off] = s;
    }

    f32x4 acc2[2][4] = {};   // GEMM2 accumulator, persists across halves

    for (int half = 0; half < 2; ++half) {
        // ---- GEMM1 for this N-half (cols half*256 .. +256) ----
        f32x4 acc1[2][4] = {};
        for (int s = 0; s < 8; ++s) {
            int k0 = s * 32;
            #pragma unroll
            for (int i = 0; i < 2; ++i) {
                int lin = tid + i * 512;
                int n = lin >> 2, kc = (lin & 3) << 3;
                *(short8*)&Bst[n * 40 + kc] =
                    *(const short8*)&W1T[(size_t)(half * 256 + n) * 256 + k0 + kc];
            }
            __syncthreads();
            short8 af[2], bf[4];
            #pragma unroll
            for (int mi = 0; mi < 2; ++mi)
                af[mi] = *(const short8*)&A_u[(wm * 32 + mi * 16 + (lane & 15)) * 264 + k0 + ((lane >> 4) << 3)];
            #pragma unroll
            for (int ni = 0; ni < 4; ++ni)
                bf[ni] = *(const short8*)&Bst[(wn * 64 + ni * 16 + (lane & 15)) * 40 + ((lane >> 4) << 3)];
            #pragma unroll
            for (int mi = 0; mi < 2; ++mi)
                #pragma unroll
                for (int ni = 0; ni < 4; ++ni)
                    acc1[mi][ni] = __builtin_amdgcn_mfma_f32_16x16x32_bf16(af[mi], bf[ni], acc1[mi][ni], 0, 0, 0);
            __syncthreads();
        }
        // acc1 -> BuF (fp32)
        #pragma unroll
        for (int mi = 0; mi < 2; ++mi) {
            int rb = wm * 32 + mi * 16 + ((lane >> 4) << 2);
            #pragma unroll
            for (int ni = 0; ni < 4; ++ni) {
                int col = wn * 64 + ni * 16 + (lane & 15);
                #pragma unroll
                for (int r = 0; r < 4; ++r)
                    BuF[(rb + r) * 260 + col] = acc1[mi][ni][r];
            }
        }
        __syncthreads();

        // ---- scan with exact carry init; 2-way time split per channel ----
        if (tid < 256) {
            int ch = tid & 127;
            int pgl = half * 128 + ch;
            float2 a = ((const float2*)Abar)[pgl];
            if (tid < 128) {
                // rows 0..31, init = carry
                float2 x = ((const float2*)carry)[(size_t)c * 256 + pgl];
                #pragma unroll 8
                for (int r = 0; r < 32; ++r) {
                    float2 bu = *(const float2*)&BuF[r * 260 + 2 * ch];
                    float xr = fmaf(a.x, x.x, fmaf(-a.y, x.y, bu.x));
                    float xi = fmaf(a.x, x.y, fmaf(a.y, x.x, bu.y));
                    x = make_float2(xr, xi);
                    *(unsigned int*)&XSh[r * 264 + 2 * ch] =
                        (unsigned int)f2bf(xr) | ((unsigned int)f2bf(xi) << 16);
                }
                sEnd[ch] = x;
            } else {
                // rows 32..63, local (init 0), write back fp32
                float2 y = make_float2(0.0f, 0.0f);
                #pragma unroll 8
                for (int r = 32; r < 64; ++r) {
                    float2 bu = *(const float2*)&BuF[r * 260 + 2 * ch];
                    float yr = fmaf(a.x, y.x, fmaf(-a.y, y.y, bu.x));
                    float yi = fmaf(a.x, y.y, fmaf(a.y, y.x, bu.y));
                    y = make_float2(yr, yi);
                    *(float2*)&BuF[r * 260 + 2 * ch] = y;
                }
            }
        }
        __syncthreads();
        if (tid >= 128 && tid < 256) {
            // fixup: x_true[r] = y_loc[r] + a^{r-31} * xEnd
            int ch = tid & 127;
            int pgl = half * 128 + ch;
            float2 a = ((const float2*)Abar)[pgl];
            float2 xe = sEnd[ch];
            float2 wgt = a;   // a^1
            #pragma unroll 8
            for (int r = 32; r < 64; ++r) {
                float2 y = *(const float2*)&BuF[r * 260 + 2 * ch];
                float vr = y.x + wgt.x * xe.x - wgt.y * xe.y;
                float vi = y.y + wgt.x * xe.y + wgt.y * xe.x;
                *(unsigned int*)&XSh[r * 264 + 2 * ch] =
                    (unsigned int)f2bf(vr) | ((unsigned int)f2bf(vi) << 16);
                float t = wgt.x * a.x - wgt.y * a.y;
                wgt.y = wgt.x * a.y + wgt.y * a.x;
                wgt.x = t;
            }
        }
        __syncthreads();

        // ---- GEMM2 partial: K-range [half*256, half*256+256) ----
        for (int s = 0; s < 8; ++s) {
            int k0 = s * 32;
            #pragma unroll
            for (int i = 0; i < 2; ++i) {
                int lin = tid + i * 512;
                int n = lin >> 2, kc = (lin & 3) << 3;
                *(short8*)&Bst[n * 40 + kc] =
                    *(const short8*)&W2T[(size_t)n * 512 + half * 256 + k0 + kc];
            }
            __syncthreads();
            short8 af[2], bf[4];
            #pragma unroll
            for (int mi = 0; mi < 2; ++mi)
                af[mi] = *(const short8*)&XSh[(wm * 32 + mi * 16 + (lane & 15)) * 264 + k0 + ((lane >> 4) << 3)];
            #pragma unroll
            for (int ni = 0; ni < 4; ++ni)
                bf[ni] = *(const short8*)&Bst[(wn * 64 + ni * 16 + (lane & 15)) * 40 + ((lane >> 4) << 3)];
            #pragma unroll
            for (int mi = 0; mi < 2; ++mi)
                #pragma unroll
                for (int ni = 0; ni < 4; ++ni)
                    acc2[mi][ni] = __builtin_amdgcn_mfma_f32_16x16x32_bf16(af[mi], bf[ni], acc2[mi][ni], 0, 0, 0);
            __syncthreads();
        }
    }

    // ---- epilogue: out = acc2 + D*u (fp32 u re-read, likely L2-hot) ----
    #pragma unroll
    for (int ni = 0; ni < 4; ++ni) {
        int col = wn * 64 + ni * 16 + (lane & 15);
        float d = Dv[col];
        #pragma unroll
        for (int mi = 0; mi < 2; ++mi) {
            int rb = wm * 32 + mi * 16 + ((lane >> 4) << 2);
            #pragma unroll
            for (int r = 0; r < 4; ++r) {
                int grow = m0 + rb + r;
                Out[(size_t)grow * 256 + col] =
                    acc2[mi][ni][r] + d * U[(size_t)grow * 256 + col];
            }
        }
    }
}

// ---------------------------------------------------------------------------
extern "C" void kernel_launch(void* const* d_in, const int* in_sizes, int n_in,
                              void* d_out, int out_size, void* d_ws, size_t ws_size,
                              hipStream_t stream)
{
    const float* u        = (const float*)d_in[0];
    // d_in[1] = prev_state: provably never affects outputs (zero + cancelled)
    const float* Lambda   = (const float*)d_in[2];
    const float* B        = (const float*)d_in[3];
    const float* C        = (const float*)d_in[4];
    const float* D        = (const float*)d_in[5];
    const float* log_step = (const float*)d_in[6];
    float* out = (float*)d_out;

    // workspace layout (floats)
    float* powt      = (float*)d_ws;                     // 65*512
    float* Abar      = powt + 65 * 512;                  // 512
    float* g         = Abar + 512;                       // 512
    float* local_end = g + 512;                          // 512*512
    float* carry     = local_end + (size_t)NCHUNK * 512; // 512*512
    short* W1T       = (short*)(carry + (size_t)NCHUNK * 512); // 512*256
    short* W2T       = W1T + 512 * 256;                  // 256*512

    s5_prep1<<<1, 256, 0, stream>>>(Lambda, log_step, Abar, g, powt);
    s5_prep2<<<256, 256, 0, stream>>>(B, C, g, W1T, W2T);
    s5_localend<<<NCHUNK, 512, 0, stream>>>(u, W1T, Abar, powt, local_end);
    s5_scan2<<<1, 256, 0, stream>>>(local_end, carry, powt, out + (size_t)LSEQ * HDIM);
    s5_fused<<<NCHUNK, 512, 0, stream>>>(u, W1T, W2T, Abar, carry, D, out);
}

// Round 4
// 115.311 us; speedup vs baseline: 1.1695x; 1.1695x over previous
//
#include <hip/hip_runtime.h>

#define LSEQ 32768
#define HDIM 256
#define PDIM 256
#define CHUNK 64
#define NCHUNK 512   // LSEQ / CHUNK

typedef __attribute__((ext_vector_type(8))) short short8;
typedef __attribute__((ext_vector_type(4))) float f32x4;

static __device__ __forceinline__ unsigned short f2bf(float f) {
    unsigned int u = __float_as_uint(f);
    return (unsigned short)((u + 0x7FFFu + ((u >> 16) & 1u)) >> 16);
}
static __device__ __forceinline__ float bf2f(unsigned int lo16) {
    return __uint_as_float(lo16 << 16);
}

// ---------------------------------------------------------------------------
// prep (merged): grid 256 x 256 thr.
//  - every block: thread t computes discretization for channel p=t
//  - blocks 0..64: powt[b][p] = Abar_p^b via binary exponentiation
//  - block 1: writes Abar
//  - every block b: W1T row pair for p=b (recomputes g_b per thread, cheap)
//                   W2T row for h=b
// ---------------------------------------------------------------------------
__global__ void s5_prep(const float* __restrict__ Lambda,
                        const float* __restrict__ log_step,
                        const float* __restrict__ B,
                        const float* __restrict__ C,
                        float* __restrict__ Abar,
                        float* __restrict__ powt,
                        short* __restrict__ W1T,
                        short* __restrict__ W2T)
{
    const int b = blockIdx.x, t = threadIdx.x;

    // discretization for p = t (used for powt/Abar)
    {
        float lr = Lambda[2 * t], li = Lambda[2 * t + 1];
        float step = expf(log_step[t]);
        float s2 = 0.5f * step;
        float dr = 1.0f - s2 * lr, di = -s2 * li;
        float inv = 1.0f / (dr * dr + di * di);
        float blr = dr * inv, bli = -di * inv;
        float nr = 1.0f + s2 * lr, ni = s2 * li;
        float ar = blr * nr - bli * ni;
        float ai = blr * ni + bli * nr;

        if (b <= 64) {   // powt[b][t] = (ar,ai)^b
            float pr = 1.0f, pi = 0.0f;
            float br_ = ar, bi_ = ai;
            unsigned kk = (unsigned)b;
            while (kk) {
                if (kk & 1u) {
                    float tr = pr * br_ - pi * bi_;
                    pi = pr * bi_ + pi * br_;
                    pr = tr;
                }
                kk >>= 1;
                if (kk) {
                    float tr = br_ * br_ - bi_ * bi_;
                    bi_ = 2.0f * br_ * bi_;
                    br_ = tr;
                }
            }
            powt[(size_t)b * 512 + 2 * t] = pr;
            powt[(size_t)b * 512 + 2 * t + 1] = pi;
        }
        if (b == 1) { Abar[2 * t] = ar; Abar[2 * t + 1] = ai; }
    }

    // W1T rows for p = b : need g_b (recompute per thread)
    {
        float lr = Lambda[2 * b], li = Lambda[2 * b + 1];
        float step = expf(log_step[b]);
        float s2 = 0.5f * step;
        float dr = 1.0f - s2 * lr, di = -s2 * li;
        float inv = 1.0f / (dr * dr + di * di);
        float gr = dr * inv * step, gi = -di * inv * step;
        float br = B[(size_t)(b * HDIM + t) * 2];
        float bi = B[(size_t)(b * HDIM + t) * 2 + 1];
        W1T[(size_t)(2 * b) * 256 + t]     = (short)f2bf(gr * br - gi * bi);
        W1T[(size_t)(2 * b + 1) * 256 + t] = (short)f2bf(gr * bi + gi * br);
    }
    // W2T row for h = b
    {
        float cr = C[(size_t)(b * PDIM + t) * 2];
        float ci = C[(size_t)(b * PDIM + t) * 2 + 1];
        W2T[(size_t)b * 512 + 2 * t]     = (short)f2bf(cr);
        W2T[(size_t)b * 512 + 2 * t + 1] = (short)f2bf(-ci);
    }
}

// ---------------------------------------------------------------------------
// k1: fused GEMM1 (Bu = u @ W1, bf16 MFMA) + per-chunk LOCAL scan (init 0).
// Block: chunk c (64 rows) x N-half (256 of 512 cols). 256 thr / 4 waves.
// Scan is 2-segment split (rows 0-31 / 32-63) + iterative-weight fixup.
// Emits xs_local (bf16 pairs packed u32) + local_end (fp32).
// ---------------------------------------------------------------------------
__global__ __launch_bounds__(256) void s5_k1(const float* __restrict__ U,
                                             const short* __restrict__ W1T,
                                             const float* __restrict__ Abar,
                                             unsigned int* __restrict__ xs,
                                             float* __restrict__ local_end)
{
    __shared__ char smem[66560];
    short* As = (short*)smem;             // [64][264] bf16 (pad +8)
    short* Bs = (short*)(smem + 33792);   // [256][40] bf16 (pad +8)
    float* sb = (float*)smem;             // [64][256] f32, aliased after GEMM
    float2* sEndv = (float2*)(smem + 65536);  // [128]

    const int tid = threadIdx.x;
    const int lane = tid & 63, w = tid >> 6;
    const int n0 = blockIdx.x * 256;
    const int c  = blockIdx.y;
    const int m0 = c * CHUNK;

    // stage u tile -> bf16
    #pragma unroll
    for (int i = 0; i < 8; ++i) {
        int gidx = tid + i * 256;
        int row = gidx >> 5, kc = (gidx & 31) << 3;
        const float4* up = (const float4*)&U[(size_t)(m0 + row) * 256 + kc];
        float4 v0 = up[0], v1 = up[1];
        short8 s;
        s[0] = (short)f2bf(v0.x); s[1] = (short)f2bf(v0.y);
        s[2] = (short)f2bf(v0.z); s[3] = (short)f2bf(v0.w);
        s[4] = (short)f2bf(v1.x); s[5] = (short)f2bf(v1.y);
        s[6] = (short)f2bf(v1.z); s[7] = (short)f2bf(v1.w);
        *(short8*)&As[row * 264 + kc] = s;
    }

    f32x4 acc[4][4] = {};

    // stage Bs for k-step 0
    #pragma unroll
    for (int i = 0; i < 4; ++i) {
        int gidx = tid + i * 256;
        int n = gidx >> 2, kc = (gidx & 3) << 3;
        *(short8*)&Bs[n * 40 + kc] = *(const short8*)&W1T[(size_t)(n0 + n) * 256 + kc];
    }

    for (int s = 0; s < 8; ++s) {
        int k0 = s * 32;
        __syncthreads();
        short8 af[4], bfr[4];
        #pragma unroll
        for (int mi = 0; mi < 4; ++mi)
            af[mi] = *(const short8*)&As[(mi * 16 + (lane & 15)) * 264 + k0 + ((lane >> 4) << 3)];
        #pragma unroll
        for (int ni = 0; ni < 4; ++ni)
            bfr[ni] = *(const short8*)&Bs[(w * 64 + ni * 16 + (lane & 15)) * 40 + ((lane >> 4) << 3)];
        #pragma unroll
        for (int mi = 0; mi < 4; ++mi)
            #pragma unroll
            for (int ni = 0; ni < 4; ++ni)
                acc[mi][ni] = __builtin_amdgcn_mfma_f32_16x16x32_bf16(af[mi], bfr[ni], acc[mi][ni], 0, 0, 0);
        __syncthreads();
        if (s < 7) {
            int k1 = k0 + 32;
            #pragma unroll
            for (int i = 0; i < 4; ++i) {
                int gidx = tid + i * 256;
                int n = gidx >> 2, kc = (gidx & 3) << 3;
                *(short8*)&Bs[n * 40 + kc] = *(const short8*)&W1T[(size_t)(n0 + n) * 256 + k1 + kc];
            }
        }
    }

    // acc -> scan buffer (f32), aliased over As/Bs (safe: barrier above)
    #pragma unroll
    for (int mi = 0; mi < 4; ++mi) {
        int row = mi * 16 + ((lane >> 4) << 2);
        #pragma unroll
        for (int ni = 0; ni < 4; ++ni) {
            int col = w * 64 + ni * 16 + (lane & 15);
            #pragma unroll
            for (int r = 0; r < 4; ++r)
                sb[(row + r) * 256 + col] = acc[mi][ni][r];
        }
    }
    __syncthreads();

    // local scan, 2-segment split: 256 threads (128 channels x 2 segs)
    if (tid < 256) {
        int ch = tid & 127, seg = tid >> 7;
        int pgl = (n0 >> 1) + ch;
        float2 a = ((const float2*)Abar)[pgl];
        float xr = 0.0f, xi = 0.0f;
        if (seg == 0) {
            unsigned int* xsp = xs + (size_t)m0 * 256 + pgl;
            #pragma unroll 8
            for (int r = 0; r < 32; ++r) {
                float2 bu = *(const float2*)&sb[r * 256 + 2 * ch];
                float nr  = fmaf(a.x, xr, fmaf(-a.y, xi, bu.x));
                float nim = fmaf(a.x, xi, fmaf(a.y, xr, bu.y));
                xr = nr; xi = nim;
                xsp[(size_t)r * 256] = (unsigned int)f2bf(xr) | ((unsigned int)f2bf(xi) << 16);
            }
            sEndv[ch] = make_float2(xr, xi);
        } else {
            #pragma unroll 8
            for (int r = 32; r < 64; ++r) {
                float2 bu = *(const float2*)&sb[r * 256 + 2 * ch];
                float nr  = fmaf(a.x, xr, fmaf(-a.y, xi, bu.x));
                float nim = fmaf(a.x, xi, fmaf(a.y, xr, bu.y));
                xr = nr; xi = nim;
                *(float2*)&sb[r * 256 + 2 * ch] = make_float2(xr, xi);
            }
        }
    }
    __syncthreads();
    if (tid >= 128 && tid < 256) {
        int ch = tid & 127;
        int pgl = (n0 >> 1) + ch;
        float2 a = ((const float2*)Abar)[pgl];
        float2 I = sEndv[ch];
        float wr = a.x, wi = a.y;
        unsigned int* xsp = xs + (size_t)m0 * 256 + pgl;
        float xr = 0.0f, xi = 0.0f;
        #pragma unroll 8
        for (int r = 32; r < 64; ++r) {
            float2 y = *(const float2*)&sb[r * 256 + 2 * ch];
            xr = y.x + wr * I.x - wi * I.y;
            xi = y.y + wr * I.y + wi * I.x;
            xsp[(size_t)r * 256] = (unsigned int)f2bf(xr) | ((unsigned int)f2bf(xi) << 16);
            float tw = wr * a.x - wi * a.y;
            wi = wr * a.y + wi * a.x;
            wr = tw;
        }
        ((float2*)local_end)[(size_t)c * 256 + pgl] = make_float2(xr, xi);
    }
}

// ---------------------------------------------------------------------------
// scan2: carry scan over 512 chunks (batched loads to pipeline the chain)
// ---------------------------------------------------------------------------
__global__ void s5_scan2(const float* __restrict__ local_end,
                         float* __restrict__ carry,
                         const float* __restrict__ powt,
                         float* __restrict__ out_state)
{
    int p = threadIdx.x;
    float2 A = ((const float2*)powt)[CHUNK * 256 + p];   // Abar^64
    float cr = 0.0f, ci = 0.0f;
    for (int cb = 0; cb < NCHUNK; cb += 16) {
        float2 e[16];
        #pragma unroll
        for (int j = 0; j < 16; ++j)
            e[j] = ((const float2*)local_end)[(size_t)(cb + j) * 256 + p];
        #pragma unroll
        for (int j = 0; j < 16; ++j) {
            ((float2*)carry)[(size_t)(cb + j) * 256 + p] = make_float2(cr, ci);
            float nr = fmaf(A.x, cr, fmaf(-A.y, ci, e[j].x));
            float ni = fmaf(A.x, ci, fmaf(A.y, cr, e[j].y));
            cr = nr; ci = ni;
        }
    }
    out_state[2 * p] = cr;
    out_state[2 * p + 1] = ci;
}

// ---------------------------------------------------------------------------
// k2: GEMM2 ys = fix(xs) @ W2 + D*u, bf16 MFMA, fixup in fp32 during staging.
// Full-N tile 128x256 (fixup done once per row), K=512, BK=64,
// 512 threads = 8 waves (2m x 4n, each wave 64x64). Grid = 256 blocks.
// ---------------------------------------------------------------------------
__global__ __launch_bounds__(512) void s5_k2(const unsigned int* __restrict__ xs,
                                             const short* __restrict__ W2T,
                                             const float* __restrict__ carry,
                                             const float* __restrict__ powt,
                                             const float* __restrict__ Dv,
                                             const float* __restrict__ U,
                                             float* __restrict__ Out)
{
    __shared__ char smem[55296];
    short* As = (short*)smem;            // [128][72] bf16 (pad +8)
    short* Bs = (short*)(smem + 18432);  // [256][72]

    const int tid = threadIdx.x, lane = tid & 63, w = tid >> 6;
    const int wm = w >> 2, wn = w & 3;
    const int m0 = blockIdx.x * 128;
    f32x4 acc[4][4] = {};

    for (int s = 0; s < 8; ++s) {
        int k0 = s * 64;
        // --- stage A with carry fixup (fp32), convert to bf16 ---
        #pragma unroll
        for (int i = 0; i < 2; ++i) {
            int gidx = tid + i * 512;
            int row = gidx >> 3, kc = (gidx & 7) << 3;
            int grow = m0 + row;
            uint4 xv = *(const uint4*)&xs[(size_t)grow * 256 + ((k0 + kc) >> 1)];
            const float4* pwp = (const float4*)&powt[(size_t)((grow & 63) + 1) * 512 + k0 + kc];
            const float4* cvp = (const float4*)&carry[(size_t)(grow >> 6) * 512 + k0 + kc];
            float4 p0 = pwp[0], p1 = pwp[1];
            float4 c0 = cvp[0], c1 = cvp[1];
            float r0 = bf2f(xv.x & 0xffffu), i0 = bf2f(xv.x >> 16);
            float r1 = bf2f(xv.y & 0xffffu), i1 = bf2f(xv.y >> 16);
            float r2 = bf2f(xv.z & 0xffffu), i2 = bf2f(xv.z >> 16);
            float r3 = bf2f(xv.w & 0xffffu), i3 = bf2f(xv.w >> 16);
            r0 += p0.x * c0.x - p0.y * c0.y;  i0 += p0.x * c0.y + p0.y * c0.x;
            r1 += p0.z * c0.z - p0.w * c0.w;  i1 += p0.z * c0.w + p0.w * c0.z;
            r2 += p1.x * c1.x - p1.y * c1.y;  i2 += p1.x * c1.y + p1.y * c1.x;
            r3 += p1.z * c1.z - p1.w * c1.w;  i3 += p1.z * c1.w + p1.w * c1.z;
            short8 sv;
            sv[0] = (short)f2bf(r0); sv[1] = (short)f2bf(i0);
            sv[2] = (short)f2bf(r1); sv[3] = (short)f2bf(i1);
            sv[4] = (short)f2bf(r2); sv[5] = (short)f2bf(i2);
            sv[6] = (short)f2bf(r3); sv[7] = (short)f2bf(i3);
            *(short8*)&As[row * 72 + kc] = sv;
        }
        // --- stage B (plain bf16 copy from W2T) ---
        #pragma unroll
        for (int i = 0; i < 4; ++i) {
            int gidx = tid + i * 512;
            int n = gidx >> 3, kc = (gidx & 7) << 3;
            *(short8*)&Bs[n * 72 + kc] = *(const short8*)&W2T[(size_t)n * 512 + k0 + kc];
        }
        __syncthreads();
        #pragma unroll
        for (int ks = 0; ks < 2; ++ks) {
            short8 af[4], bfr[4];
            #pragma unroll
            for (int mi = 0; mi < 4; ++mi)
                af[mi] = *(const short8*)&As[(wm * 64 + mi * 16 + (lane & 15)) * 72 + ks * 32 + ((lane >> 4) << 3)];
            #pragma unroll
            for (int ni = 0; ni < 4; ++ni)
                bfr[ni] = *(const short8*)&Bs[(wn * 64 + ni * 16 + (lane & 15)) * 72 + ks * 32 + ((lane >> 4) << 3)];
            #pragma unroll
            for (int mi = 0; mi < 4; ++mi)
                #pragma unroll
                for (int ni = 0; ni < 4; ++ni)
                    acc[mi][ni] = __builtin_amdgcn_mfma_f32_16x16x32_bf16(af[mi], bfr[ni], acc[mi][ni], 0, 0, 0);
        }
        __syncthreads();
    }

    // epilogue: + D*u, fp32 out
    #pragma unroll
    for (int ni = 0; ni < 4; ++ni) {
        int col = wn * 64 + ni * 16 + (lane & 15);
        float d = Dv[col];
        #pragma unroll
        for (int mi = 0; mi < 4; ++mi) {
            int rb = m0 + wm * 64 + mi * 16 + ((lane >> 4) << 2);
            #pragma unroll
            for (int r = 0; r < 4; ++r) {
                int row = rb + r;
                Out[(size_t)row * 256 + col] = acc[mi][ni][r] + d * U[(size_t)row * 256 + col];
            }
        }
    }
}

// ---------------------------------------------------------------------------
extern "C" void kernel_launch(void* const* d_in, const int* in_sizes, int n_in,
                              void* d_out, int out_size, void* d_ws, size_t ws_size,
                              hipStream_t stream)
{
    const float* u        = (const float*)d_in[0];
    // d_in[1] = prev_state: provably never affects outputs (A_0 never enters
    // the associative-scan products; and it's zero anyway)
    const float* Lambda   = (const float*)d_in[2];
    const float* B        = (const float*)d_in[3];
    const float* C        = (const float*)d_in[4];
    const float* D        = (const float*)d_in[5];
    const float* log_step = (const float*)d_in[6];
    float* out = (float*)d_out;

    // workspace layout
    unsigned int* xs = (unsigned int*)d_ws;               // L*256 u32 (bf16 pairs) = 32 MB
    float* powt      = (float*)(xs + (size_t)LSEQ * 256); // 65*512
    float* Abar      = powt + 65 * 512;                   // 512
    float* local_end = Abar + 512;                        // 512*512
    float* carry     = local_end + (size_t)NCHUNK * 512;  // 512*512
    short* W1T       = (short*)(carry + (size_t)NCHUNK * 512); // 512*256
    short* W2T       = W1T + 512 * 256;                   // 256*512

    s5_prep<<<256, 256, 0, stream>>>(Lambda, log_step, B, C, Abar, powt, W1T, W2T);
    s5_k1<<<dim3(2, NCHUNK), 256, 0, stream>>>(u, W1T, Abar, xs, local_end);
    s5_scan2<<<1, 256, 0, stream>>>(local_end, carry, powt, out + (size_t)LSEQ * HDIM);
    s5_k2<<<256, 512, 0, stream>>>(xs, W2T, carry, powt, D, u, out);
}

// Round 5
// 98.704 us; speedup vs baseline: 1.3663x; 1.1682x over previous
//
#include <hip/hip_runtime.h>

#define LSEQ 32768
#define HDIM 256
#define PDIM 256
#define CHUNK 64
#define NCHUNK 512   // LSEQ / CHUNK

typedef __attribute__((ext_vector_type(8))) short short8;
typedef __attribute__((ext_vector_type(4))) float f32x4;

static __device__ __forceinline__ unsigned short f2bf(float f) {
    unsigned int u = __float_as_uint(f);
    return (unsigned short)((u + 0x7FFFu + ((u >> 16) & 1u)) >> 16);
}
static __device__ __forceinline__ float bf2f(unsigned int lo16) {
    return __uint_as_float(lo16 << 16);
}
// packed f32x2 -> bf16x2 in one VALU op (low word = a, high word = b)
static __device__ __forceinline__ unsigned int cvtpk_bf16(float a, float b) {
    unsigned int r;
    asm("v_cvt_pk_bf16_f32 %0, %1, %2" : "=v"(r) : "v"(a), "v"(b));
    return r;
}

// ---------------------------------------------------------------------------
// prep (merged): grid 256 x 256 thr.
//  - blocks 0..64: powt[b][p] = Abar_p^b (iterative product, matches scan numerics)
//  - block 1: writes Abar
//  - every block b: W1T row pair for p=b; W2T row for h=b
// ---------------------------------------------------------------------------
__global__ void s5_prep(const float* __restrict__ Lambda,
                        const float* __restrict__ log_step,
                        const float* __restrict__ B,
                        const float* __restrict__ C,
                        float* __restrict__ Abar,
                        float* __restrict__ powt,
                        short* __restrict__ W1T,
                        short* __restrict__ W2T)
{
    const int b = blockIdx.x, t = threadIdx.x;

    {   // discretization for p = t
        float lr = Lambda[2 * t], li = Lambda[2 * t + 1];
        float step = expf(log_step[t]);
        float s2 = 0.5f * step;
        float dr = 1.0f - s2 * lr, di = -s2 * li;
        float inv = 1.0f / (dr * dr + di * di);
        float blr = dr * inv, bli = -di * inv;
        float nr = 1.0f + s2 * lr, ni = s2 * li;
        float ar = blr * nr - bli * ni;
        float ai = blr * ni + bli * nr;

        if (b <= 64) {   // powt[b][t] = (ar,ai)^b, iterative
            float pr = 1.0f, pi = 0.0f;
            for (int k = 0; k < b; ++k) {
                float tr = pr * ar - pi * ai;
                pi = pr * ai + pi * ar;
                pr = tr;
            }
            powt[(size_t)b * 512 + 2 * t] = pr;
            powt[(size_t)b * 512 + 2 * t + 1] = pi;
        }
        if (b == 1) { Abar[2 * t] = ar; Abar[2 * t + 1] = ai; }
    }
    {   // W1T rows for p = b
        float lr = Lambda[2 * b], li = Lambda[2 * b + 1];
        float step = expf(log_step[b]);
        float s2 = 0.5f * step;
        float dr = 1.0f - s2 * lr, di = -s2 * li;
        float inv = 1.0f / (dr * dr + di * di);
        float gr = dr * inv * step, gi = -di * inv * step;
        float br = B[(size_t)(b * HDIM + t) * 2];
        float bi = B[(size_t)(b * HDIM + t) * 2 + 1];
        W1T[(size_t)(2 * b) * 256 + t]     = (short)f2bf(gr * br - gi * bi);
        W1T[(size_t)(2 * b + 1) * 256 + t] = (short)f2bf(gr * bi + gi * br);
    }
    {   // W2T row for h = b
        float cr = C[(size_t)(b * PDIM + t) * 2];
        float ci = C[(size_t)(b * PDIM + t) * 2 + 1];
        W2T[(size_t)b * 512 + 2 * t]     = (short)f2bf(cr);
        W2T[(size_t)b * 512 + 2 * t + 1] = (short)f2bf(-ci);
    }
}

// ---------------------------------------------------------------------------
// k1: fused GEMM1 (Bu = u @ W1, bf16 MFMA) + per-chunk LOCAL scan (init 0).
// Block: chunk c (64 rows) x N-half (256 of 512 cols). 256 thr / 4 waves.
// ---------------------------------------------------------------------------
__global__ __launch_bounds__(256) void s5_k1(const float* __restrict__ U,
                                             const short* __restrict__ W1T,
                                             const float* __restrict__ Abar,
                                             unsigned int* __restrict__ xs,
                                             float* __restrict__ local_end)
{
    __shared__ char smem[66560];
    short* As = (short*)smem;             // [64][264] bf16 (pad +8)
    short* Bs = (short*)(smem + 33792);   // [256][40] bf16 (pad +8)
    float* sb = (float*)smem;             // [64][256] f32, aliased after GEMM
    float2* sEndv = (float2*)(smem + 65536);  // [128]

    const int tid = threadIdx.x;
    const int lane = tid & 63, w = tid >> 6;
    const int n0 = blockIdx.x * 256;
    const int c  = blockIdx.y;
    const int m0 = c * CHUNK;

    // stage u tile -> bf16 (packed cvt)
    #pragma unroll
    for (int i = 0; i < 8; ++i) {
        int gidx = tid + i * 256;
        int row = gidx >> 5, kc = (gidx & 31) << 3;
        const float4* up = (const float4*)&U[(size_t)(m0 + row) * 256 + kc];
        float4 v0 = up[0], v1 = up[1];
        uint4 wv;
        wv.x = cvtpk_bf16(v0.x, v0.y);
        wv.y = cvtpk_bf16(v0.z, v0.w);
        wv.z = cvtpk_bf16(v1.x, v1.y);
        wv.w = cvtpk_bf16(v1.z, v1.w);
        *(uint4*)&As[row * 264 + kc] = wv;
    }

    f32x4 acc[4][4] = {};

    // stage Bs for k-step 0
    #pragma unroll
    for (int i = 0; i < 4; ++i) {
        int gidx = tid + i * 256;
        int n = gidx >> 2, kc = (gidx & 3) << 3;
        *(short8*)&Bs[n * 40 + kc] = *(const short8*)&W1T[(size_t)(n0 + n) * 256 + kc];
    }

    for (int s = 0; s < 8; ++s) {
        int k0 = s * 32;
        __syncthreads();
        short8 af[4], bfr[4];
        #pragma unroll
        for (int mi = 0; mi < 4; ++mi)
            af[mi] = *(const short8*)&As[(mi * 16 + (lane & 15)) * 264 + k0 + ((lane >> 4) << 3)];
        #pragma unroll
        for (int ni = 0; ni < 4; ++ni)
            bfr[ni] = *(const short8*)&Bs[(w * 64 + ni * 16 + (lane & 15)) * 40 + ((lane >> 4) << 3)];
        #pragma unroll
        for (int mi = 0; mi < 4; ++mi)
            #pragma unroll
            for (int ni = 0; ni < 4; ++ni)
                acc[mi][ni] = __builtin_amdgcn_mfma_f32_16x16x32_bf16(af[mi], bfr[ni], acc[mi][ni], 0, 0, 0);
        __syncthreads();
        if (s < 7) {
            int k1 = k0 + 32;
            #pragma unroll
            for (int i = 0; i < 4; ++i) {
                int gidx = tid + i * 256;
                int n = gidx >> 2, kc = (gidx & 3) << 3;
                *(short8*)&Bs[n * 40 + kc] = *(const short8*)&W1T[(size_t)(n0 + n) * 256 + k1 + kc];
            }
        }
    }

    // acc -> scan buffer (f32), aliased over As/Bs
    #pragma unroll
    for (int mi = 0; mi < 4; ++mi) {
        int row = mi * 16 + ((lane >> 4) << 2);
        #pragma unroll
        for (int ni = 0; ni < 4; ++ni) {
            int col = w * 64 + ni * 16 + (lane & 15);
            #pragma unroll
            for (int r = 0; r < 4; ++r)
                sb[(row + r) * 256 + col] = acc[mi][ni][r];
        }
    }
    __syncthreads();

    // local scan, 2-segment split: 256 threads (128 channels x 2 segs)
    {
        int ch = tid & 127, seg = tid >> 7;
        int pgl = (n0 >> 1) + ch;
        float2 a = ((const float2*)Abar)[pgl];
        float xr = 0.0f, xi = 0.0f;
        if (seg == 0) {
            unsigned int* xsp = xs + (size_t)m0 * 256 + pgl;
            #pragma unroll 8
            for (int r = 0; r < 32; ++r) {
                float2 bu = *(const float2*)&sb[r * 256 + 2 * ch];
                float nr  = fmaf(a.x, xr, fmaf(-a.y, xi, bu.x));
                float nim = fmaf(a.x, xi, fmaf(a.y, xr, bu.y));
                xr = nr; xi = nim;
                xsp[(size_t)r * 256] = cvtpk_bf16(xr, xi);
            }
            sEndv[ch] = make_float2(xr, xi);
        } else {
            #pragma unroll 8
            for (int r = 32; r < 64; ++r) {
                float2 bu = *(const float2*)&sb[r * 256 + 2 * ch];
                float nr  = fmaf(a.x, xr, fmaf(-a.y, xi, bu.x));
                float nim = fmaf(a.x, xi, fmaf(a.y, xr, bu.y));
                xr = nr; xi = nim;
                *(float2*)&sb[r * 256 + 2 * ch] = make_float2(xr, xi);
            }
        }
    }
    __syncthreads();
    if (tid >= 128) {
        int ch = tid & 127;
        int pgl = (n0 >> 1) + ch;
        float2 a = ((const float2*)Abar)[pgl];
        float2 I = sEndv[ch];
        float wr = a.x, wi = a.y;
        unsigned int* xsp = xs + (size_t)m0 * 256 + pgl;
        float xr = 0.0f, xi = 0.0f;
        #pragma unroll 8
        for (int r = 32; r < 64; ++r) {
            float2 y = *(const float2*)&sb[r * 256 + 2 * ch];
            xr = y.x + wr * I.x - wi * I.y;
            xi = y.y + wr * I.y + wi * I.x;
            xsp[(size_t)r * 256] = cvtpk_bf16(xr, xi);
            float tw = wr * a.x - wi * a.y;
            wi = wr * a.y + wi * a.x;
            wr = tw;
        }
        ((float2*)local_end)[(size_t)c * 256 + pgl] = make_float2(xr, xi);
    }
}

// ---------------------------------------------------------------------------
// scan2: carry scan over 512 chunks (batched loads to pipeline the chain)
// ---------------------------------------------------------------------------
__global__ void s5_scan2(const float* __restrict__ local_end,
                         float* __restrict__ carry,
                         const float* __restrict__ powt,
                         float* __restrict__ out_state)
{
    int p = threadIdx.x;
    float2 A = ((const float2*)powt)[CHUNK * 256 + p];   // Abar^64
    float cr = 0.0f, ci = 0.0f;
    for (int cb = 0; cb < NCHUNK; cb += 16) {
        float2 e[16];
        #pragma unroll
        for (int j = 0; j < 16; ++j)
            e[j] = ((const float2*)local_end)[(size_t)(cb + j) * 256 + p];
        #pragma unroll
        for (int j = 0; j < 16; ++j) {
            ((float2*)carry)[(size_t)(cb + j) * 256 + p] = make_float2(cr, ci);
            float nr = fmaf(A.x, cr, fmaf(-A.y, ci, e[j].x));
            float ni = fmaf(A.x, ci, fmaf(A.y, cr, e[j].y));
            cr = nr; ci = ni;
        }
    }
    out_state[2 * p] = cr;
    out_state[2 * p + 1] = ci;
}

// ---------------------------------------------------------------------------
// k2: GEMM2 ys = fix(xs) @ W2 + D*u. 64x256 tile (one chunk per block),
// K=512, BK=32, double-buffered staging, 256 thr / 4 waves, grid 512.
// Carry vector cached in LDS; fixup once per row; float4 epilogue via LDS.
// ---------------------------------------------------------------------------
__global__ __launch_bounds__(256) void s5_k2(const unsigned int* __restrict__ xs,
                                             const short* __restrict__ W2T,
                                             const float* __restrict__ carry,
                                             const float* __restrict__ powt,
                                             const float* __restrict__ Dv,
                                             const float* __restrict__ U,
                                             float* __restrict__ Out)
{
    __shared__ char smem[53248];
    // As0 [0,5120) As1 [5120,10240) Bs0 [10240,30720) Bs1 [30720,51200) carry [51200,53248)
    short* As0 = (short*)smem;
    short* As1 = (short*)(smem + 5120);
    short* Bs0 = (short*)(smem + 10240);
    short* Bs1 = (short*)(smem + 30720);
    float* carryLds = (float*)(smem + 51200);
    float* sb = (float*)smem;   // [32][260] f32 epilogue buffer (33280 B)

    const int tid = threadIdx.x, lane = tid & 63, w = tid >> 6;
    const int c  = blockIdx.x;        // chunk index
    const int m0 = c * 64;
    f32x4 acc[4][4] = {};

    // A-stage thread mapping (fixed): row = tid>>2 (0..63), kc = (tid&3)*8
    const int arow = tid >> 2;
    const int akc  = (tid & 3) << 3;

    // preload carry[c] (512 floats) to LDS
    ((float2*)carryLds)[tid] = ((const float2*)carry)[(size_t)c * 256 + tid];
    __syncthreads();

    // ---- staging helpers ----
    #define STAGE_A(S, AS)                                                        \
    {                                                                             \
        int k0_ = (S) * 32;                                                       \
        uint4 xv = *(const uint4*)&xs[(size_t)(m0 + arow) * 256 + ((k0_ + akc) >> 1)]; \
        const float4* pwp = (const float4*)&powt[(size_t)(arow + 1) * 512 + k0_ + akc]; \
        float4 p0 = pwp[0], p1 = pwp[1];                                          \
        float4 c0 = *(const float4*)&carryLds[k0_ + akc];                         \
        float4 c1 = *(const float4*)&carryLds[k0_ + akc + 4];                     \
        float r0 = bf2f(xv.x & 0xffffu), i0 = bf2f(xv.x >> 16);                   \
        float r1 = bf2f(xv.y & 0xffffu), i1 = bf2f(xv.y >> 16);                   \
        float r2 = bf2f(xv.z & 0xffffu), i2 = bf2f(xv.z >> 16);                   \
        float r3 = bf2f(xv.w & 0xffffu), i3 = bf2f(xv.w >> 16);                   \
        r0 += p0.x * c0.x - p0.y * c0.y;  i0 += p0.x * c0.y + p0.y * c0.x;        \
        r1 += p0.z * c0.z - p0.w * c0.w;  i1 += p0.z * c0.w + p0.w * c0.z;        \
        r2 += p1.x * c1.x - p1.y * c1.y;  i2 += p1.x * c1.y + p1.y * c1.x;        \
        r3 += p1.z * c1.z - p1.w * c1.w;  i3 += p1.z * c1.w + p1.w * c1.z;        \
        uint4 wv;                                                                 \
        wv.x = cvtpk_bf16(r0, i0); wv.y = cvtpk_bf16(r1, i1);                     \
        wv.z = cvtpk_bf16(r2, i2); wv.w = cvtpk_bf16(r3, i3);                     \
        *(uint4*)&(AS)[arow * 40 + akc] = wv;                                     \
    }

    #define STAGE_B(S, BS)                                                        \
    {                                                                             \
        int k0_ = (S) * 32;                                                       \
        _Pragma("unroll")                                                         \
        for (int i_ = 0; i_ < 4; ++i_) {                                          \
            int lin = tid + i_ * 256;                                             \
            int n_ = lin >> 2, kc_ = (lin & 3) << 3;                              \
            *(short8*)&(BS)[n_ * 40 + kc_] =                                      \
                *(const short8*)&W2T[(size_t)n_ * 512 + k0_ + kc_];               \
        }                                                                         \
    }

    #define COMPUTE(AS, BS)                                                       \
    {                                                                             \
        short8 af[4], bfr[4];                                                     \
        _Pragma("unroll")                                                         \
        for (int mi = 0; mi < 4; ++mi)                                            \
            af[mi] = *(const short8*)&(AS)[(mi * 16 + (lane & 15)) * 40 + ((lane >> 4) << 3)]; \
        _Pragma("unroll")                                                         \
        for (int ni = 0; ni < 4; ++ni)                                            \
            bfr[ni] = *(const short8*)&(BS)[(w * 64 + ni * 16 + (lane & 15)) * 40 + ((lane >> 4) << 3)]; \
        _Pragma("unroll")                                                         \
        for (int mi = 0; mi < 4; ++mi)                                            \
            _Pragma("unroll")                                                     \
            for (int ni = 0; ni < 4; ++ni)                                        \
                acc[mi][ni] = __builtin_amdgcn_mfma_f32_16x16x32_bf16(af[mi], bfr[ni], acc[mi][ni], 0, 0, 0); \
    }

    STAGE_A(0, As0); STAGE_B(0, Bs0);
    __syncthreads();

    for (int s = 0; s < 16; s += 2) {
        STAGE_A(s + 1, As1); STAGE_B(s + 1, Bs1);
        COMPUTE(As0, Bs0);
        __syncthreads();
        if (s + 2 < 16) { STAGE_A(s + 2, As0); STAGE_B(s + 2, Bs0); }
        COMPUTE(As1, Bs1);
        __syncthreads();
    }

    // ---- epilogue: LDS transpose -> float4 stores (+ D*u) ----
    #pragma unroll
    for (int pass = 0; pass < 2; ++pass) {
        #pragma unroll
        for (int mi2 = 0; mi2 < 2; ++mi2) {
            int mi = pass * 2 + mi2;
            int lr0 = mi2 * 16 + ((lane >> 4) << 2);
            #pragma unroll
            for (int ni = 0; ni < 4; ++ni) {
                int col = w * 64 + ni * 16 + (lane & 15);
                #pragma unroll
                for (int r = 0; r < 4; ++r)
                    sb[(lr0 + r) * 260 + col] = acc[mi][ni][r];
            }
        }
        __syncthreads();
        #pragma unroll
        for (int j = 0; j < 8; ++j) {
            int idx = tid + j * 256;
            int lrow = idx >> 6, c4 = (idx & 63) << 2;
            int grow = m0 + pass * 32 + lrow;
            float4 v  = *(const float4*)&sb[lrow * 260 + c4];
            float4 uv = *(const float4*)&U[(size_t)grow * 256 + c4];
            float4 dv = *(const float4*)&Dv[c4];
            float4 o;
            o.x = v.x + dv.x * uv.x;
            o.y = v.y + dv.y * uv.y;
            o.z = v.z + dv.z * uv.z;
            o.w = v.w + dv.w * uv.w;
            *(float4*)&Out[(size_t)grow * 256 + c4] = o;
        }
        __syncthreads();
    }
    #undef STAGE_A
    #undef STAGE_B
    #undef COMPUTE
}

// ---------------------------------------------------------------------------
extern "C" void kernel_launch(void* const* d_in, const int* in_sizes, int n_in,
                              void* d_out, int out_size, void* d_ws, size_t ws_size,
                              hipStream_t stream)
{
    const float* u        = (const float*)d_in[0];
    // d_in[1] = prev_state: provably never affects outputs (A_0 never enters
    // the associative-scan products; and it's zero anyway)
    const float* Lambda   = (const float*)d_in[2];
    const float* B        = (const float*)d_in[3];
    const float* C        = (const float*)d_in[4];
    const float* D        = (const float*)d_in[5];
    const float* log_step = (const float*)d_in[6];
    float* out = (float*)d_out;

    // workspace layout
    unsigned int* xs = (unsigned int*)d_ws;               // L*256 u32 (bf16 pairs) = 32 MB
    float* powt      = (float*)(xs + (size_t)LSEQ * 256); // 65*512
    float* Abar      = powt + 65 * 512;                   // 512
    float* local_end = Abar + 512;                        // 512*512
    float* carry     = local_end + (size_t)NCHUNK * 512;  // 512*512
    short* W1T       = (short*)(carry + (size_t)NCHUNK * 512); // 512*256
    short* W2T       = W1T + 512 * 256;                   // 256*512

    s5_prep<<<256, 256, 0, stream>>>(Lambda, log_step, B, C, Abar, powt, W1T, W2T);
    s5_k1<<<dim3(2, NCHUNK), 256, 0, stream>>>(u, W1T, Abar, xs, local_end);
    s5_scan2<<<1, 256, 0, stream>>>(local_end, carry, powt, out + (size_t)LSEQ * HDIM);
    s5_k2<<<NCHUNK, 256, 0, stream>>>(xs, W2T, carry, powt, D, u, out);
}

// Round 6
// 97.123 us; speedup vs baseline: 1.3885x; 1.0163x over previous
//
#include <hip/hip_runtime.h>

#define LSEQ 32768
#define HDIM 256
#define PDIM 256
#define CHUNK 64
#define NCHUNK 512   // LSEQ / CHUNK

typedef __attribute__((ext_vector_type(8))) short short8;
typedef __attribute__((ext_vector_type(4))) float f32x4;

static __device__ __forceinline__ unsigned short f2bf(float f) {
    unsigned int u = __float_as_uint(f);
    return (unsigned short)((u + 0x7FFFu + ((u >> 16) & 1u)) >> 16);
}
static __device__ __forceinline__ float bf2f(unsigned int lo16) {
    return __uint_as_float(lo16 << 16);
}
// packed f32x2 -> bf16x2 in one VALU op (low word = a, high word = b)
static __device__ __forceinline__ unsigned int cvtpk_bf16(float a, float b) {
    unsigned int r;
    asm("v_cvt_pk_bf16_f32 %0, %1, %2" : "=v"(r) : "v"(a), "v"(b));
    return r;
}

// ---------------------------------------------------------------------------
// prep (merged): grid 256 x 256 thr.
//  - blocks 0..64: powt[b][p] = Abar_p^b (iterative product, matches scan numerics)
//  - block 1: writes Abar
//  - every block b: W1T row pair for p=b; W2T row for h=b
// ---------------------------------------------------------------------------
__global__ void s5_prep(const float* __restrict__ Lambda,
                        const float* __restrict__ log_step,
                        const float* __restrict__ B,
                        const float* __restrict__ C,
                        float* __restrict__ Abar,
                        float* __restrict__ powt,
                        short* __restrict__ W1T,
                        short* __restrict__ W2T)
{
    const int b = blockIdx.x, t = threadIdx.x;

    {   // discretization for p = t
        float lr = Lambda[2 * t], li = Lambda[2 * t + 1];
        float step = expf(log_step[t]);
        float s2 = 0.5f * step;
        float dr = 1.0f - s2 * lr, di = -s2 * li;
        float inv = 1.0f / (dr * dr + di * di);
        float blr = dr * inv, bli = -di * inv;
        float nr = 1.0f + s2 * lr, ni = s2 * li;
        float ar = blr * nr - bli * ni;
        float ai = blr * ni + bli * nr;

        if (b <= 64) {   // powt[b][t] = (ar,ai)^b, iterative
            float pr = 1.0f, pi = 0.0f;
            for (int k = 0; k < b; ++k) {
                float tr = pr * ar - pi * ai;
                pi = pr * ai + pi * ar;
                pr = tr;
            }
            powt[(size_t)b * 512 + 2 * t] = pr;
            powt[(size_t)b * 512 + 2 * t + 1] = pi;
        }
        if (b == 1) { Abar[2 * t] = ar; Abar[2 * t + 1] = ai; }
    }
    {   // W1T rows for p = b
        float lr = Lambda[2 * b], li = Lambda[2 * b + 1];
        float step = expf(log_step[b]);
        float s2 = 0.5f * step;
        float dr = 1.0f - s2 * lr, di = -s2 * li;
        float inv = 1.0f / (dr * dr + di * di);
        float gr = dr * inv * step, gi = -di * inv * step;
        float br = B[(size_t)(b * HDIM + t) * 2];
        float bi = B[(size_t)(b * HDIM + t) * 2 + 1];
        W1T[(size_t)(2 * b) * 256 + t]     = (short)f2bf(gr * br - gi * bi);
        W1T[(size_t)(2 * b + 1) * 256 + t] = (short)f2bf(gr * bi + gi * br);
    }
    {   // W2T row for h = b
        float cr = C[(size_t)(b * PDIM + t) * 2];
        float ci = C[(size_t)(b * PDIM + t) * 2 + 1];
        W2T[(size_t)b * 512 + 2 * t]     = (short)f2bf(cr);
        W2T[(size_t)b * 512 + 2 * t + 1] = (short)f2bf(-ci);
    }
}

// ---------------------------------------------------------------------------
// k1: fused GEMM1 (Bu = u @ W1, bf16 MFMA) + per-chunk LOCAL scan (init 0).
// Block: chunk c (64 rows) x N-half (256 of 512 cols). 256 thr / 4 waves.
// Bs double-buffered: one barrier per K-step, W1T loads in flight across MFMA.
// ---------------------------------------------------------------------------
__global__ __launch_bounds__(256) void s5_k1(const float* __restrict__ U,
                                             const short* __restrict__ W1T,
                                             const float* __restrict__ Abar,
                                             unsigned int* __restrict__ xs,
                                             float* __restrict__ local_end)
{
    __shared__ char smem[75776];
    short* As  = (short*)smem;             // [64][264] bf16 (pad +8), 33792 B
    short* Bs0 = (short*)(smem + 33792);   // [256][40] bf16, 20480 B
    short* Bs1 = (short*)(smem + 54272);   // [256][40] bf16, 20480 B
    float* sb  = (float*)smem;             // [64][260] f32 aliased after GEMM (66560 B)
    float2* sEndv = (float2*)(smem + 74752);  // [128]

    const int tid = threadIdx.x;
    const int lane = tid & 63, w = tid >> 6;
    const int n0 = blockIdx.x * 256;
    const int c  = blockIdx.y;
    const int m0 = c * CHUNK;

    // stage u tile -> bf16 (packed cvt)
    #pragma unroll
    for (int i = 0; i < 8; ++i) {
        int gidx = tid + i * 256;
        int row = gidx >> 5, kc = (gidx & 31) << 3;
        const float4* up = (const float4*)&U[(size_t)(m0 + row) * 256 + kc];
        float4 v0 = up[0], v1 = up[1];
        uint4 wv;
        wv.x = cvtpk_bf16(v0.x, v0.y);
        wv.y = cvtpk_bf16(v0.z, v0.w);
        wv.z = cvtpk_bf16(v1.x, v1.y);
        wv.w = cvtpk_bf16(v1.z, v1.w);
        *(uint4*)&As[row * 264 + kc] = wv;
    }

    f32x4 acc[4][4] = {};

    #define K1_STAGE_B(S, BS)                                                     \
    {                                                                             \
        int k0_ = (S) * 32;                                                       \
        _Pragma("unroll")                                                         \
        for (int i_ = 0; i_ < 4; ++i_) {                                          \
            int gidx_ = tid + i_ * 256;                                           \
            int n_ = gidx_ >> 2, kc_ = (gidx_ & 3) << 3;                          \
            *(short8*)&(BS)[n_ * 40 + kc_] =                                      \
                *(const short8*)&W1T[(size_t)(n0 + n_) * 256 + k0_ + kc_];        \
        }                                                                         \
    }

    #define K1_COMPUTE(S, BS)                                                     \
    {                                                                             \
        int k0_ = (S) * 32;                                                       \
        short8 af[4], bfr[4];                                                     \
        _Pragma("unroll")                                                         \
        for (int mi = 0; mi < 4; ++mi)                                            \
            af[mi] = *(const short8*)&As[(mi * 16 + (lane & 15)) * 264 + k0_ + ((lane >> 4) << 3)]; \
        _Pragma("unroll")                                                         \
        for (int ni = 0; ni < 4; ++ni)                                            \
            bfr[ni] = *(const short8*)&(BS)[(w * 64 + ni * 16 + (lane & 15)) * 40 + ((lane >> 4) << 3)]; \
        _Pragma("unroll")                                                         \
        for (int mi = 0; mi < 4; ++mi)                                            \
            _Pragma("unroll")                                                     \
            for (int ni = 0; ni < 4; ++ni)                                        \
                acc[mi][ni] = __builtin_amdgcn_mfma_f32_16x16x32_bf16(af[mi], bfr[ni], acc[mi][ni], 0, 0, 0); \
    }

    K1_STAGE_B(0, Bs0);
    __syncthreads();
    for (int s = 0; s < 8; s += 2) {
        K1_STAGE_B(s + 1, Bs1);
        K1_COMPUTE(s, Bs0);
        __syncthreads();
        if (s + 2 < 8) K1_STAGE_B(s + 2, Bs0);
        K1_COMPUTE(s + 1, Bs1);
        __syncthreads();
    }

    // acc -> scan buffer (f32, pad 260 to break 4-way write conflict)
    #pragma unroll
    for (int mi = 0; mi < 4; ++mi) {
        int row = mi * 16 + ((lane >> 4) << 2);
        #pragma unroll
        for (int ni = 0; ni < 4; ++ni) {
            int col = w * 64 + ni * 16 + (lane & 15);
            #pragma unroll
            for (int r = 0; r < 4; ++r)
                sb[(row + r) * 260 + col] = acc[mi][ni][r];
        }
    }
    __syncthreads();

    // local scan, 2-segment split: 256 threads (128 channels x 2 segs)
    {
        int ch = tid & 127, seg = tid >> 7;
        int pgl = (n0 >> 1) + ch;
        float2 a = ((const float2*)Abar)[pgl];
        float xr = 0.0f, xi = 0.0f;
        if (seg == 0) {
            unsigned int* xsp = xs + (size_t)m0 * 256 + pgl;
            #pragma unroll 8
            for (int r = 0; r < 32; ++r) {
                float2 bu = *(const float2*)&sb[r * 260 + 2 * ch];
                float nr  = fmaf(a.x, xr, fmaf(-a.y, xi, bu.x));
                float nim = fmaf(a.x, xi, fmaf(a.y, xr, bu.y));
                xr = nr; xi = nim;
                xsp[(size_t)r * 256] = cvtpk_bf16(xr, xi);
            }
            sEndv[ch] = make_float2(xr, xi);
        } else {
            #pragma unroll 8
            for (int r = 32; r < 64; ++r) {
                float2 bu = *(const float2*)&sb[r * 260 + 2 * ch];
                float nr  = fmaf(a.x, xr, fmaf(-a.y, xi, bu.x));
                float nim = fmaf(a.x, xi, fmaf(a.y, xr, bu.y));
                xr = nr; xi = nim;
                *(float2*)&sb[r * 260 + 2 * ch] = make_float2(xr, xi);
            }
        }
    }
    __syncthreads();
    if (tid >= 128) {
        int ch = tid & 127;
        int pgl = (n0 >> 1) + ch;
        float2 a = ((const float2*)Abar)[pgl];
        float2 I = sEndv[ch];
        float wr = a.x, wi = a.y;
        unsigned int* xsp = xs + (size_t)m0 * 256 + pgl;
        float xr = 0.0f, xi = 0.0f;
        #pragma unroll 8
        for (int r = 32; r < 64; ++r) {
            float2 y = *(const float2*)&sb[r * 260 + 2 * ch];
            xr = y.x + wr * I.x - wi * I.y;
            xi = y.y + wr * I.y + wi * I.x;
            xsp[(size_t)r * 256] = cvtpk_bf16(xr, xi);
            float tw = wr * a.x - wi * a.y;
            wi = wr * a.y + wi * a.x;
            wr = tw;
        }
        ((float2*)local_end)[(size_t)c * 256 + pgl] = make_float2(xr, xi);
    }
    #undef K1_STAGE_B
    #undef K1_COMPUTE
}

// ---------------------------------------------------------------------------
// scan2: carry scan over 512 chunks (batched loads to pipeline the chain)
// ---------------------------------------------------------------------------
__global__ void s5_scan2(const float* __restrict__ local_end,
                         float* __restrict__ carry,
                         const float* __restrict__ powt,
                         float* __restrict__ out_state)
{
    int p = threadIdx.x;
    float2 A = ((const float2*)powt)[CHUNK * 256 + p];   // Abar^64
    float cr = 0.0f, ci = 0.0f;
    for (int cb = 0; cb < NCHUNK; cb += 16) {
        float2 e[16];
        #pragma unroll
        for (int j = 0; j < 16; ++j)
            e[j] = ((const float2*)local_end)[(size_t)(cb + j) * 256 + p];
        #pragma unroll
        for (int j = 0; j < 16; ++j) {
            ((float2*)carry)[(size_t)(cb + j) * 256 + p] = make_float2(cr, ci);
            float nr = fmaf(A.x, cr, fmaf(-A.y, ci, e[j].x));
            float ni = fmaf(A.x, ci, fmaf(A.y, cr, e[j].y));
            cr = nr; ci = ni;
        }
    }
    out_state[2 * p] = cr;
    out_state[2 * p + 1] = ci;
}

// ---------------------------------------------------------------------------
// k2: GEMM2 ys = fix(xs) @ W2 + D*u. 64x256 tile (one chunk per block),
// K=512, BK=32, double-buffered staging, 256 thr / 4 waves, grid 512.
// Carry vector cached in LDS; fixup once per row; float4 epilogue via LDS.
// ---------------------------------------------------------------------------
__global__ __launch_bounds__(256) void s5_k2(const unsigned int* __restrict__ xs,
                                             const short* __restrict__ W2T,
                                             const float* __restrict__ carry,
                                             const float* __restrict__ powt,
                                             const float* __restrict__ Dv,
                                             const float* __restrict__ U,
                                             float* __restrict__ Out)
{
    __shared__ char smem[53248];
    // As0 [0,5120) As1 [5120,10240) Bs0 [10240,30720) Bs1 [30720,51200) carry [51200,53248)
    short* As0 = (short*)smem;
    short* As1 = (short*)(smem + 5120);
    short* Bs0 = (short*)(smem + 10240);
    short* Bs1 = (short*)(smem + 30720);
    float* carryLds = (float*)(smem + 51200);
    float* sb = (float*)smem;   // [32][260] f32 epilogue buffer (33280 B)

    const int tid = threadIdx.x, lane = tid & 63, w = tid >> 6;
    const int c  = blockIdx.x;        // chunk index
    const int m0 = c * 64;
    f32x4 acc[4][4] = {};

    // A-stage thread mapping (fixed): row = tid>>2 (0..63), kc = (tid&3)*8
    const int arow = tid >> 2;
    const int akc  = (tid & 3) << 3;

    // preload carry[c] (512 floats) to LDS
    ((float2*)carryLds)[tid] = ((const float2*)carry)[(size_t)c * 256 + tid];
    __syncthreads();

    // ---- staging helpers ----
    #define STAGE_A(S, AS)                                                        \
    {                                                                             \
        int k0_ = (S) * 32;                                                       \
        uint4 xv = *(const uint4*)&xs[(size_t)(m0 + arow) * 256 + ((k0_ + akc) >> 1)]; \
        const float4* pwp = (const float4*)&powt[(size_t)(arow + 1) * 512 + k0_ + akc]; \
        float4 p0 = pwp[0], p1 = pwp[1];                                          \
        float4 c0 = *(const float4*)&carryLds[k0_ + akc];                         \
        float4 c1 = *(const float4*)&carryLds[k0_ + akc + 4];                     \
        float r0 = bf2f(xv.x & 0xffffu), i0 = bf2f(xv.x >> 16);                   \
        float r1 = bf2f(xv.y & 0xffffu), i1 = bf2f(xv.y >> 16);                   \
        float r2 = bf2f(xv.z & 0xffffu), i2 = bf2f(xv.z >> 16);                   \
        float r3 = bf2f(xv.w & 0xffffu), i3 = bf2f(xv.w >> 16);                   \
        r0 += p0.x * c0.x - p0.y * c0.y;  i0 += p0.x * c0.y + p0.y * c0.x;        \
        r1 += p0.z * c0.z - p0.w * c0.w;  i1 += p0.z * c0.w + p0.w * c0.z;        \
        r2 += p1.x * c1.x - p1.y * c1.y;  i2 += p1.x * c1.y + p1.y * c1.x;        \
        r3 += p1.z * c1.z - p1.w * c1.w;  i3 += p1.z * c1.w + p1.w * c1.z;        \
        uint4 wv;                                                                 \
        wv.x = cvtpk_bf16(r0, i0); wv.y = cvtpk_bf16(r1, i1);                     \
        wv.z = cvtpk_bf16(r2, i2); wv.w = cvtpk_bf16(r3, i3);                     \
        *(uint4*)&(AS)[arow * 40 + akc] = wv;                                     \
    }

    #define STAGE_B(S, BS)                                                        \
    {                                                                             \
        int k0_ = (S) * 32;                                                       \
        _Pragma("unroll")                                                         \
        for (int i_ = 0; i_ < 4; ++i_) {                                          \
            int lin = tid + i_ * 256;                                             \
            int n_ = lin >> 2, kc_ = (lin & 3) << 3;                              \
            *(short8*)&(BS)[n_ * 40 + kc_] =                                      \
                *(const short8*)&W2T[(size_t)n_ * 512 + k0_ + kc_];               \
        }                                                                         \
    }

    #define COMPUTE(AS, BS)                                                       \
    {                                                                             \
        short8 af[4], bfr[4];                                                     \
        _Pragma("unroll")                                                         \
        for (int mi = 0; mi < 4; ++mi)                                            \
            af[mi] = *(const short8*)&(AS)[(mi * 16 + (lane & 15)) * 40 + ((lane >> 4) << 3)]; \
        _Pragma("unroll")                                                         \
        for (int ni = 0; ni < 4; ++ni)                                            \
            bfr[ni] = *(const short8*)&(BS)[(w * 64 + ni * 16 + (lane & 15)) * 40 + ((lane >> 4) << 3)]; \
        _Pragma("unroll")                                                         \
        for (int mi = 0; mi < 4; ++mi)                                            \
            _Pragma("unroll")                                                     \
            for (int ni = 0; ni < 4; ++ni)                                        \
                acc[mi][ni] = __builtin_amdgcn_mfma_f32_16x16x32_bf16(af[mi], bfr[ni], acc[mi][ni], 0, 0, 0); \
    }

    STAGE_A(0, As0); STAGE_B(0, Bs0);
    __syncthreads();

    for (int s = 0; s < 16; s += 2) {
        STAGE_A(s + 1, As1); STAGE_B(s + 1, Bs1);
        COMPUTE(As0, Bs0);
        __syncthreads();
        if (s + 2 < 16) { STAGE_A(s + 2, As0); STAGE_B(s + 2, Bs0); }
        COMPUTE(As1, Bs1);
        __syncthreads();
    }

    // ---- epilogue: LDS transpose -> float4 stores (+ D*u) ----
    #pragma unroll
    for (int pass = 0; pass < 2; ++pass) {
        #pragma unroll
        for (int mi2 = 0; mi2 < 2; ++mi2) {
            int mi = pass * 2 + mi2;
            int lr0 = mi2 * 16 + ((lane >> 4) << 2);
            #pragma unroll
            for (int ni = 0; ni < 4; ++ni) {
                int col = w * 64 + ni * 16 + (lane & 15);
                #pragma unroll
                for (int r = 0; r < 4; ++r)
                    sb[(lr0 + r) * 260 + col] = acc[mi][ni][r];
            }
        }
        __syncthreads();
        #pragma unroll
        for (int j = 0; j < 8; ++j) {
            int idx = tid + j * 256;
            int lrow = idx >> 6, c4 = (idx & 63) << 2;
            int grow = m0 + pass * 32 + lrow;
            float4 v  = *(const float4*)&sb[lrow * 260 + c4];
            float4 uv = *(const float4*)&U[(size_t)grow * 256 + c4];
            float4 dv = *(const float4*)&Dv[c4];
            float4 o;
            o.x = v.x + dv.x * uv.x;
            o.y = v.y + dv.y * uv.y;
            o.z = v.z + dv.z * uv.z;
            o.w = v.w + dv.w * uv.w;
            *(float4*)&Out[(size_t)grow * 256 + c4] = o;
        }
        __syncthreads();
    }
    #undef STAGE_A
    #undef STAGE_B
    #undef COMPUTE
}

// ---------------------------------------------------------------------------
extern "C" void kernel_launch(void* const* d_in, const int* in_sizes, int n_in,
                              void* d_out, int out_size, void* d_ws, size_t ws_size,
                              hipStream_t stream)
{
    const float* u        = (const float*)d_in[0];
    // d_in[1] = prev_state: provably never affects outputs (A_0 never enters
    // the associative-scan products; and it's zero anyway)
    const float* Lambda   = (const float*)d_in[2];
    const float* B        = (const float*)d_in[3];
    const float* C        = (const float*)d_in[4];
    const float* D        = (const float*)d_in[5];
    const float* log_step = (const float*)d_in[6];
    float* out = (float*)d_out;

    // workspace layout
    unsigned int* xs = (unsigned int*)d_ws;               // L*256 u32 (bf16 pairs) = 32 MB
    float* powt      = (float*)(xs + (size_t)LSEQ * 256); // 65*512
    float* Abar      = powt + 65 * 512;                   // 512
    float* local_end = Abar + 512;                        // 512*512
    float* carry     = local_end + (size_t)NCHUNK * 512;  // 512*512
    short* W1T       = (short*)(carry + (size_t)NCHUNK * 512); // 512*256
    short* W2T       = W1T + 512 * 256;                   // 256*512

    s5_prep<<<256, 256, 0, stream>>>(Lambda, log_step, B, C, Abar, powt, W1T, W2T);
    s5_k1<<<dim3(2, NCHUNK), 256, 0, stream>>>(u, W1T, Abar, xs, local_end);
    s5_scan2<<<1, 256, 0, stream>>>(local_end, carry, powt, out + (size_t)LSEQ * HDIM);
    s5_k2<<<NCHUNK, 256, 0, stream>>>(xs, W2T, carry, powt, D, u, out);
}

// Round 8
// 95.978 us; speedup vs baseline: 1.4051x; 1.0119x over previous
//
#include <hip/hip_runtime.h>

#define LSEQ 32768
#define HDIM 256
#define PDIM 256
#define CHUNK 64
#define NCHUNK 512   // LSEQ / CHUNK

typedef __attribute__((ext_vector_type(8))) short short8;
typedef __attribute__((ext_vector_type(4))) float f32x4;

static __device__ __forceinline__ unsigned short f2bf(float f) {
    unsigned int u = __float_as_uint(f);
    return (unsigned short)((u + 0x7FFFu + ((u >> 16) & 1u)) >> 16);
}
static __device__ __forceinline__ float bf2f(unsigned int lo16) {
    return __uint_as_float(lo16 << 16);
}
// packed f32x2 -> bf16x2 in one VALU op (low word = a, high word = b)
static __device__ __forceinline__ unsigned int cvtpk_bf16(float a, float b) {
    unsigned int r;
    asm("v_cvt_pk_bf16_f32 %0, %1, %2" : "=v"(r) : "v"(a), "v"(b));
    return r;
}

// fragment-major weight index: one frag = 64 lanes x 8 contiguous bf16 (=16B).
// element (n,k) of an [N][K] matrix stored as 16x16x32 MFMA B-fragments:
//   frag = (k>>5)*(N/16) + (n>>4);  lane = (n&15) + (((k>>3)&3)<<4);  e = k&7
static __device__ __forceinline__ size_t fragidx(int n, int k, int ntiles) {
    return ((size_t)((k >> 5) * ntiles + (n >> 4))) * 512 +
           (size_t)(((n & 15) + (((k >> 3) & 3) << 4)) * 8 + (k & 7));
}

// ---------------------------------------------------------------------------
// prep: grid 256 x 256 thr.
//  - blocks 0..64: powt[b][p] = Abar_p^b (iterative, matches scan numerics)
//  - block 1: Abar
//  - block b: W1T row pair n=2b,2b+1 (row-major, for k1's LDS staging)
//             W2F row h=b (fragment-major, for k2's direct global B)
// ---------------------------------------------------------------------------
__global__ void s5_prep(const float* __restrict__ Lambda,
                        const float* __restrict__ log_step,
                        const float* __restrict__ B,
                        const float* __restrict__ C,
                        float* __restrict__ Abar,
                        float* __restrict__ powt,
                        short* __restrict__ W1T,
                        short* __restrict__ W2F)
{
    const int b = blockIdx.x, t = threadIdx.x;

    {   // discretization for p = t
        float lr = Lambda[2 * t], li = Lambda[2 * t + 1];
        float step = expf(log_step[t]);
        float s2 = 0.5f * step;
        float dr = 1.0f - s2 * lr, di = -s2 * li;
        float inv = 1.0f / (dr * dr + di * di);
        float blr = dr * inv, bli = -di * inv;
        float nr = 1.0f + s2 * lr, ni = s2 * li;
        float ar = blr * nr - bli * ni;
        float ai = blr * ni + bli * nr;

        if (b <= 64) {   // powt[b][t] = (ar,ai)^b, iterative
            float pr = 1.0f, pi = 0.0f;
            for (int k = 0; k < b; ++k) {
                float tr = pr * ar - pi * ai;
                pi = pr * ai + pi * ar;
                pr = tr;
            }
            powt[(size_t)b * 512 + 2 * t] = pr;
            powt[(size_t)b * 512 + 2 * t + 1] = pi;
        }
        if (b == 1) { Abar[2 * t] = ar; Abar[2 * t + 1] = ai; }
    }
    {   // W1T rows for p = b (row-major [512][256])
        float lr = Lambda[2 * b], li = Lambda[2 * b + 1];
        float step = expf(log_step[b]);
        float s2 = 0.5f * step;
        float dr = 1.0f - s2 * lr, di = -s2 * li;
        float inv = 1.0f / (dr * dr + di * di);
        float gr = dr * inv * step, gi = -di * inv * step;
        float br = B[(size_t)(b * HDIM + t) * 2];
        float bi = B[(size_t)(b * HDIM + t) * 2 + 1];
        W1T[(size_t)(2 * b) * 256 + t]     = (short)f2bf(gr * br - gi * bi);
        W1T[(size_t)(2 * b + 1) * 256 + t] = (short)f2bf(gr * bi + gi * br);
    }
    {   // W2F row h = b (fragment-major, N=256 -> ntiles=16, K=512)
        float cr = C[(size_t)(b * PDIM + t) * 2];
        float ci = C[(size_t)(b * PDIM + t) * 2 + 1];
        W2F[fragidx(b, 2 * t,     16)] = (short)f2bf(cr);
        W2F[fragidx(b, 2 * t + 1, 16)] = (short)f2bf(-ci);
    }
}

// ---------------------------------------------------------------------------
// k1: fused GEMM1 (Bu = u @ W1, bf16 MFMA) + per-chunk LOCAL scan (init 0).
// Block: chunk c (64 rows) x N-half (256 of 512 cols). 256 thr / 4 waves.
// Bs double-buffered. (r6-proven version, unchanged.)
// ---------------------------------------------------------------------------
__global__ __launch_bounds__(256) void s5_k1(const float* __restrict__ U,
                                             const short* __restrict__ W1T,
                                             const float* __restrict__ Abar,
                                             unsigned int* __restrict__ xs,
                                             float* __restrict__ local_end)
{
    __shared__ char smem[75776];
    short* As  = (short*)smem;             // [64][264] bf16 (pad +8), 33792 B
    short* Bs0 = (short*)(smem + 33792);   // [256][40] bf16, 20480 B
    short* Bs1 = (short*)(smem + 54272);   // [256][40] bf16, 20480 B
    float* sb  = (float*)smem;             // [64][260] f32 aliased after GEMM
    float2* sEndv = (float2*)(smem + 74752);  // [128]

    const int tid = threadIdx.x;
    const int lane = tid & 63, w = tid >> 6;
    const int n0 = blockIdx.x * 256;
    const int c  = blockIdx.y;
    const int m0 = c * CHUNK;

    // stage u tile -> bf16 (packed cvt)
    #pragma unroll
    for (int i = 0; i < 8; ++i) {
        int gidx = tid + i * 256;
        int row = gidx >> 5, kc = (gidx & 31) << 3;
        const float4* up = (const float4*)&U[(size_t)(m0 + row) * 256 + kc];
        float4 v0 = up[0], v1 = up[1];
        uint4 wv;
        wv.x = cvtpk_bf16(v0.x, v0.y);
        wv.y = cvtpk_bf16(v0.z, v0.w);
        wv.z = cvtpk_bf16(v1.x, v1.y);
        wv.w = cvtpk_bf16(v1.z, v1.w);
        *(uint4*)&As[row * 264 + kc] = wv;
    }

    f32x4 acc[4][4] = {};

    #define K1_STAGE_B(S, BS)                                                     \
    {                                                                             \
        int k0_ = (S) * 32;                                                       \
        _Pragma("unroll")                                                         \
        for (int i_ = 0; i_ < 4; ++i_) {                                          \
            int gidx_ = tid + i_ * 256;                                           \
            int n_ = gidx_ >> 2, kc_ = (gidx_ & 3) << 3;                          \
            *(short8*)&(BS)[n_ * 40 + kc_] =                                      \
                *(const short8*)&W1T[(size_t)(n0 + n_) * 256 + k0_ + kc_];        \
        }                                                                         \
    }

    #define K1_COMPUTE(S, BS)                                                     \
    {                                                                             \
        int k0_ = (S) * 32;                                                       \
        short8 af[4], bfr[4];                                                     \
        _Pragma("unroll")                                                         \
        for (int mi = 0; mi < 4; ++mi)                                            \
            af[mi] = *(const short8*)&As[(mi * 16 + (lane & 15)) * 264 + k0_ + ((lane >> 4) << 3)]; \
        _Pragma("unroll")                                                         \
        for (int ni = 0; ni < 4; ++ni)                                            \
            bfr[ni] = *(const short8*)&(BS)[(w * 64 + ni * 16 + (lane & 15)) * 40 + ((lane >> 4) << 3)]; \
        _Pragma("unroll")                                                         \
        for (int mi = 0; mi < 4; ++mi)                                            \
            _Pragma("unroll")                                                     \
            for (int ni = 0; ni < 4; ++ni)                                        \
                acc[mi][ni] = __builtin_amdgcn_mfma_f32_16x16x32_bf16(af[mi], bfr[ni], acc[mi][ni], 0, 0, 0); \
    }

    K1_STAGE_B(0, Bs0);
    __syncthreads();
    for (int s = 0; s < 8; s += 2) {
        K1_STAGE_B(s + 1, Bs1);
        K1_COMPUTE(s, Bs0);
        __syncthreads();
        if (s + 2 < 8) K1_STAGE_B(s + 2, Bs0);
        K1_COMPUTE(s + 1, Bs1);
        __syncthreads();
    }

    // acc -> scan buffer (f32, pad 260)
    #pragma unroll
    for (int mi = 0; mi < 4; ++mi) {
        int row = mi * 16 + ((lane >> 4) << 2);
        #pragma unroll
        for (int ni = 0; ni < 4; ++ni) {
            int col = w * 64 + ni * 16 + (lane & 15);
            #pragma unroll
            for (int r = 0; r < 4; ++r)
                sb[(row + r) * 260 + col] = acc[mi][ni][r];
        }
    }
    __syncthreads();

    // local scan, 2-segment split: 256 threads (128 channels x 2 segs)
    {
        int ch = tid & 127, seg = tid >> 7;
        int pgl = (n0 >> 1) + ch;
        float2 a = ((const float2*)Abar)[pgl];
        float xr = 0.0f, xi = 0.0f;
        if (seg == 0) {
            unsigned int* xsp = xs + (size_t)m0 * 256 + pgl;
            #pragma unroll 8
            for (int r = 0; r < 32; ++r) {
                float2 bu = *(const float2*)&sb[r * 260 + 2 * ch];
                float nr  = fmaf(a.x, xr, fmaf(-a.y, xi, bu.x));
                float nim = fmaf(a.x, xi, fmaf(a.y, xr, bu.y));
                xr = nr; xi = nim;
                xsp[(size_t)r * 256] = cvtpk_bf16(xr, xi);
            }
            sEndv[ch] = make_float2(xr, xi);
        } else {
            #pragma unroll 8
            for (int r = 32; r < 64; ++r) {
                float2 bu = *(const float2*)&sb[r * 260 + 2 * ch];
                float nr  = fmaf(a.x, xr, fmaf(-a.y, xi, bu.x));
                float nim = fmaf(a.x, xi, fmaf(a.y, xr, bu.y));
                xr = nr; xi = nim;
                *(float2*)&sb[r * 260 + 2 * ch] = make_float2(xr, xi);
            }
        }
    }
    __syncthreads();
    if (tid >= 128) {
        int ch = tid & 127;
        int pgl = (n0 >> 1) + ch;
        float2 a = ((const float2*)Abar)[pgl];
        float2 I = sEndv[ch];
        float wr = a.x, wi = a.y;
        unsigned int* xsp = xs + (size_t)m0 * 256 + pgl;
        float xr = 0.0f, xi = 0.0f;
        #pragma unroll 8
        for (int r = 32; r < 64; ++r) {
            float2 y = *(const float2*)&sb[r * 260 + 2 * ch];
            xr = y.x + wr * I.x - wi * I.y;
            xi = y.y + wr * I.y + wi * I.x;
            xsp[(size_t)r * 256] = cvtpk_bf16(xr, xi);
            float tw = wr * a.x - wi * a.y;
            wi = wr * a.y + wi * a.x;
            wr = tw;
        }
        ((float2*)local_end)[(size_t)c * 256 + pgl] = make_float2(xr, xi);
    }
    #undef K1_STAGE_B
    #undef K1_COMPUTE
}

// ---------------------------------------------------------------------------
// scan2: carry scan over 512 chunks (r6-proven version, unchanged)
// ---------------------------------------------------------------------------
__global__ void s5_scan2(const float* __restrict__ local_end,
                         float* __restrict__ carry,
                         const float* __restrict__ powt,
                         float* __restrict__ out_state)
{
    int p = threadIdx.x;
    float2 A = ((const float2*)powt)[CHUNK * 256 + p];   // Abar^64
    float cr = 0.0f, ci = 0.0f;
    for (int cb = 0; cb < NCHUNK; cb += 16) {
        float2 e[16];
        #pragma unroll
        for (int j = 0; j < 16; ++j)
            e[j] = ((const float2*)local_end)[(size_t)(cb + j) * 256 + p];
        #pragma unroll
        for (int j = 0; j < 16; ++j) {
            ((float2*)carry)[(size_t)(cb + j) * 256 + p] = make_float2(cr, ci);
            float nr = fmaf(A.x, cr, fmaf(-A.y, ci, e[j].x));
            float ni = fmaf(A.x, ci, fmaf(A.y, cr, e[j].y));
            cr = nr; ci = ni;
        }
    }
    out_state[2 * p] = cr;
    out_state[2 * p + 1] = ci;
}

// ---------------------------------------------------------------------------
// k2: GEMM2 ys = fix(xs) @ W2 + D*u. 64x256 tile, K=512, BK=32, As dbuf with
// fixup during staging; B-fragments DIRECT from global fragment-major W2F
// (no LDS B-staging). LDS 33.3 KB. grid 512 x 256 thr.
// ---------------------------------------------------------------------------
__global__ __launch_bounds__(256) void s5_k2(const unsigned int* __restrict__ xs,
                                             const short* __restrict__ W2F,
                                             const float* __restrict__ carry,
                                             const float* __restrict__ powt,
                                             const float* __restrict__ Dv,
                                             const float* __restrict__ U,
                                             float* __restrict__ Out)
{
    __shared__ char smem[33280];
    short* As0 = (short*)smem;                    // [64][40] bf16, 5120 B
    short* As1 = (short*)(smem + 5120);           // [64][40]
    float* carryLds = (float*)(smem + 10240);     // 512 f32, 2048 B
    float* sb = (float*)smem;                     // [32][260] f32 epilogue (alias)

    const int tid = threadIdx.x, lane = tid & 63, w = tid >> 6;
    const int c  = blockIdx.x;
    const int m0 = c * 64;
    f32x4 acc[4][4] = {};

    const int arow = tid >> 2;
    const int akc  = (tid & 3) << 3;

    ((float2*)carryLds)[tid] = ((const float2*)carry)[(size_t)c * 256 + tid];
    __syncthreads();

    #define STAGE_A(S, AS)                                                        \
    {                                                                             \
        int k0_ = (S) * 32;                                                       \
        uint4 xv = *(const uint4*)&xs[(size_t)(m0 + arow) * 256 + ((k0_ + akc) >> 1)]; \
        const float4* pwp = (const float4*)&powt[(size_t)(arow + 1) * 512 + k0_ + akc]; \
        float4 p0 = pwp[0], p1 = pwp[1];                                          \
        float4 c0 = *(const float4*)&carryLds[k0_ + akc];                         \
        float4 c1 = *(const float4*)&carryLds[k0_ + akc + 4];                     \
        float r0 = bf2f(xv.x & 0xffffu), i0 = bf2f(xv.x >> 16);                   \
        float r1 = bf2f(xv.y & 0xffffu), i1 = bf2f(xv.y >> 16);                   \
        float r2 = bf2f(xv.z & 0xffffu), i2 = bf2f(xv.z >> 16);                   \
        float r3 = bf2f(xv.w & 0xffffu), i3 = bf2f(xv.w >> 16);                   \
        r0 += p0.x * c0.x - p0.y * c0.y;  i0 += p0.x * c0.y + p0.y * c0.x;        \
        r1 += p0.z * c0.z - p0.w * c0.w;  i1 += p0.z * c0.w + p0.w * c0.z;        \
        r2 += p1.x * c1.x - p1.y * c1.y;  i2 += p1.x * c1.y + p1.y * c1.x;        \
        r3 += p1.z * c1.z - p1.w * c1.w;  i3 += p1.z * c1.w + p1.w * c1.z;        \
        uint4 wv;                                                                 \
        wv.x = cvtpk_bf16(r0, i0); wv.y = cvtpk_bf16(r1, i1);                     \
        wv.z = cvtpk_bf16(r2, i2); wv.w = cvtpk_bf16(r3, i3);                     \
        *(uint4*)&(AS)[arow * 40 + akc] = wv;                                     \
    }

    #define COMPUTE(S, AS)                                                        \
    {                                                                             \
        short8 af[4], bfr[4];                                                     \
        _Pragma("unroll")                                                         \
        for (int mi = 0; mi < 4; ++mi)                                            \
            af[mi] = *(const short8*)&(AS)[(mi * 16 + (lane & 15)) * 40 + ((lane >> 4) << 3)]; \
        _Pragma("unroll")                                                         \
        for (int ni = 0; ni < 4; ++ni)                                            \
            bfr[ni] = *(const short8*)&W2F[(size_t)((S) * 16 + w * 4 + ni) * 512 + lane * 8]; \
        _Pragma("unroll")                                                         \
        for (int mi = 0; mi < 4; ++mi)                                            \
            _Pragma("unroll")                                                     \
            for (int ni = 0; ni < 4; ++ni)                                        \
                acc[mi][ni] = __builtin_amdgcn_mfma_f32_16x16x32_bf16(af[mi], bfr[ni], acc[mi][ni], 0, 0, 0); \
    }

    STAGE_A(0, As0);
    __syncthreads();

    for (int s = 0; s < 16; s += 2) {
        STAGE_A(s + 1, As1);
        COMPUTE(s, As0);
        __syncthreads();
        if (s + 2 < 16) STAGE_A(s + 2, As0);
        COMPUTE(s + 1, As1);
        __syncthreads();
    }

    // ---- epilogue: LDS transpose -> float4 stores (+ D*u) ----
    #pragma unroll
    for (int pass = 0; pass < 2; ++pass) {
        #pragma unroll
        for (int mi2 = 0; mi2 < 2; ++mi2) {
            int mi = pass * 2 + mi2;
            int lr0 = mi2 * 16 + ((lane >> 4) << 2);
            #pragma unroll
            for (int ni = 0; ni < 4; ++ni) {
                int col = w * 64 + ni * 16 + (lane & 15);
                #pragma unroll
                for (int r = 0; r < 4; ++r)
                    sb[(lr0 + r) * 260 + col] = acc[mi][ni][r];
            }
        }
        __syncthreads();
        #pragma unroll
        for (int j = 0; j < 8; ++j) {
            int idx = tid + j * 256;
            int lrow = idx >> 6, c4 = (idx & 63) << 2;
            int grow = m0 + pass * 32 + lrow;
            float4 v  = *(const float4*)&sb[lrow * 260 + c4];
            float4 uv = *(const float4*)&U[(size_t)grow * 256 + c4];
            float4 dv = *(const float4*)&Dv[c4];
            float4 o;
            o.x = v.x + dv.x * uv.x;
            o.y = v.y + dv.y * uv.y;
            o.z = v.z + dv.z * uv.z;
            o.w = v.w + dv.w * uv.w;
            *(float4*)&Out[(size_t)grow * 256 + c4] = o;
        }
        __syncthreads();
    }
    #undef STAGE_A
    #undef COMPUTE
}

// ---------------------------------------------------------------------------
extern "C" void kernel_launch(void* const* d_in, const int* in_sizes, int n_in,
                              void* d_out, int out_size, void* d_ws, size_t ws_size,
                              hipStream_t stream)
{
    const float* u        = (const float*)d_in[0];
    // d_in[1] = prev_state: provably never affects outputs (A_0 never enters
    // the associative-scan products; and it's zero anyway)
    const float* Lambda   = (const float*)d_in[2];
    const float* B        = (const float*)d_in[3];
    const float* C        = (const float*)d_in[4];
    const float* D        = (const float*)d_in[5];
    const float* log_step = (const float*)d_in[6];
    float* out = (float*)d_out;

    // workspace layout
    unsigned int* xs = (unsigned int*)d_ws;               // L*256 u32 (bf16 pairs) = 32 MB
    float* powt      = (float*)(xs + (size_t)LSEQ * 256); // 65*512
    float* Abar      = powt + 65 * 512;                   // 512
    float* local_end = Abar + 512;                        // 512*512
    float* carry     = local_end + (size_t)NCHUNK * 512;  // 512*512
    short* W1T       = (short*)(carry + (size_t)NCHUNK * 512); // 512*256
    short* W2F       = W1T + 512 * 256;                   // 256*512

    s5_prep<<<256, 256, 0, stream>>>(Lambda, log_step, B, C, Abar, powt, W1T, W2F);
    s5_k1<<<dim3(2, NCHUNK), 256, 0, stream>>>(u, W1T, Abar, xs, local_end);
    s5_scan2<<<1, 256, 0, stream>>>(local_end, carry, powt, out + (size_t)LSEQ * HDIM);
    s5_k2<<<NCHUNK, 256, 0, stream>>>(xs, W2F, carry, powt, D, u, out);
}

// Round 9
// 95.584 us; speedup vs baseline: 1.4109x; 1.0041x over previous
//
#include <hip/hip_runtime.h>

#define LSEQ 32768
#define HDIM 256
#define PDIM 256
#define CHUNK 64
#define NCHUNK 512   // LSEQ / CHUNK

typedef __attribute__((ext_vector_type(8))) short short8;
typedef __attribute__((ext_vector_type(4))) float f32x4;

static __device__ __forceinline__ unsigned short f2bf(float f) {
    unsigned int u = __float_as_uint(f);
    return (unsigned short)((u + 0x7FFFu + ((u >> 16) & 1u)) >> 16);
}
static __device__ __forceinline__ float bf2f(unsigned int lo16) {
    return __uint_as_float(lo16 << 16);
}
// packed f32x2 -> bf16x2 in one VALU op (low word = a, high word = b)
static __device__ __forceinline__ unsigned int cvtpk_bf16(float a, float b) {
    unsigned int r;
    asm("v_cvt_pk_bf16_f32 %0, %1, %2" : "=v"(r) : "v"(a), "v"(b));
    return r;
}

// fragment-major weight index: one frag = 64 lanes x 8 contiguous bf16 (=16B).
// element (n,k) of an [N][K] matrix stored as 16x16x32 MFMA B-fragments:
//   frag = (k>>5)*(N/16) + (n>>4);  lane = (n&15) + (((k>>3)&3)<<4);  e = k&7
// VALIDATED on-device in round 8 (k2 direct-global B).
static __device__ __forceinline__ size_t fragidx(int n, int k, int ntiles) {
    return ((size_t)((k >> 5) * ntiles + (n >> 4))) * 512 +
           (size_t)(((n & 15) + (((k >> 3) & 3) << 4)) * 8 + (k & 7));
}

// ---------------------------------------------------------------------------
// prep: grid 256 x 256 thr.
//  - blocks 0..64: powt[b][p] = Abar_p^b (iterative, matches scan numerics)
//  - block 1: Abar
//  - block b: W1F rows n=2b,2b+1 (fragment-major, ntiles=32, K=256)
//             W2F row h=b (fragment-major, ntiles=16, K=512)
// ---------------------------------------------------------------------------
__global__ void s5_prep(const float* __restrict__ Lambda,
                        const float* __restrict__ log_step,
                        const float* __restrict__ B,
                        const float* __restrict__ C,
                        float* __restrict__ Abar,
                        float* __restrict__ powt,
                        short* __restrict__ W1F,
                        short* __restrict__ W2F)
{
    const int b = blockIdx.x, t = threadIdx.x;

    {   // discretization for p = t
        float lr = Lambda[2 * t], li = Lambda[2 * t + 1];
        float step = expf(log_step[t]);
        float s2 = 0.5f * step;
        float dr = 1.0f - s2 * lr, di = -s2 * li;
        float inv = 1.0f / (dr * dr + di * di);
        float blr = dr * inv, bli = -di * inv;
        float nr = 1.0f + s2 * lr, ni = s2 * li;
        float ar = blr * nr - bli * ni;
        float ai = blr * ni + bli * nr;

        if (b <= 64) {   // powt[b][t] = (ar,ai)^b, iterative
            float pr = 1.0f, pi = 0.0f;
            for (int k = 0; k < b; ++k) {
                float tr = pr * ar - pi * ai;
                pi = pr * ai + pi * ar;
                pr = tr;
            }
            powt[(size_t)b * 512 + 2 * t] = pr;
            powt[(size_t)b * 512 + 2 * t + 1] = pi;
        }
        if (b == 1) { Abar[2 * t] = ar; Abar[2 * t + 1] = ai; }
    }
    {   // W1F rows for p = b (fragment-major, N=512 -> ntiles=32, K=256)
        float lr = Lambda[2 * b], li = Lambda[2 * b + 1];
        float step = expf(log_step[b]);
        float s2 = 0.5f * step;
        float dr = 1.0f - s2 * lr, di = -s2 * li;
        float inv = 1.0f / (dr * dr + di * di);
        float gr = dr * inv * step, gi = -di * inv * step;
        float br = B[(size_t)(b * HDIM + t) * 2];
        float bi = B[(size_t)(b * HDIM + t) * 2 + 1];
        W1F[fragidx(2 * b,     t, 32)] = (short)f2bf(gr * br - gi * bi);
        W1F[fragidx(2 * b + 1, t, 32)] = (short)f2bf(gr * bi + gi * br);
    }
    {   // W2F row h = b (fragment-major, N=256 -> ntiles=16, K=512)
        float cr = C[(size_t)(b * PDIM + t) * 2];
        float ci = C[(size_t)(b * PDIM + t) * 2 + 1];
        W2F[fragidx(b, 2 * t,     16)] = (short)f2bf(cr);
        W2F[fragidx(b, 2 * t + 1, 16)] = (short)f2bf(-ci);
    }
}

// ---------------------------------------------------------------------------
// k1: fused GEMM1 (Bu = u @ W1, bf16 MFMA) + per-chunk LOCAL scan (init 0).
// Block: chunk c (64 rows) x N-half (256 of 512 cols). 256 thr / 4 waves.
// B-fragments DIRECT from global fragment-major W1F -> K-loop is barrier-free.
// ---------------------------------------------------------------------------
__global__ __launch_bounds__(256) void s5_k1(const float* __restrict__ U,
                                             const short* __restrict__ W1F,
                                             const float* __restrict__ Abar,
                                             unsigned int* __restrict__ xs,
                                             float* __restrict__ local_end)
{
    __shared__ char smem[67584];
    short* As = (short*)smem;             // [64][264] bf16 (pad +8), 33792 B
    float* sb = (float*)smem;             // [64][260] f32 aliased after GEMM (66560 B)
    float2* sEndv = (float2*)(smem + 66560);  // [128]

    const int tid = threadIdx.x;
    const int lane = tid & 63, w = tid >> 6;
    const int n0 = blockIdx.x * 256;
    const int ntile0 = n0 >> 4;           // 0 or 16
    const int c  = blockIdx.y;
    const int m0 = c * CHUNK;

    // stage u tile -> bf16 (packed cvt)
    #pragma unroll
    for (int i = 0; i < 8; ++i) {
        int gidx = tid + i * 256;
        int row = gidx >> 5, kc = (gidx & 31) << 3;
        const float4* up = (const float4*)&U[(size_t)(m0 + row) * 256 + kc];
        float4 v0 = up[0], v1 = up[1];
        uint4 wv;
        wv.x = cvtpk_bf16(v0.x, v0.y);
        wv.y = cvtpk_bf16(v0.z, v0.w);
        wv.z = cvtpk_bf16(v1.x, v1.y);
        wv.w = cvtpk_bf16(v1.z, v1.w);
        *(uint4*)&As[row * 264 + kc] = wv;
    }
    __syncthreads();

    f32x4 acc[4][4] = {};

    // barrier-free K-loop: A frags from LDS, B frags direct from W1F (L2)
    for (int s = 0; s < 8; ++s) {
        int k0 = s * 32;
        short8 af[4], bfr[4];
        #pragma unroll
        for (int mi = 0; mi < 4; ++mi)
            af[mi] = *(const short8*)&As[(mi * 16 + (lane & 15)) * 264 + k0 + ((lane >> 4) << 3)];
        #pragma unroll
        for (int ni = 0; ni < 4; ++ni)
            bfr[ni] = *(const short8*)&W1F[(size_t)(s * 32 + ntile0 + w * 4 + ni) * 512 + lane * 8];
        #pragma unroll
        for (int mi = 0; mi < 4; ++mi)
            #pragma unroll
            for (int ni = 0; ni < 4; ++ni)
                acc[mi][ni] = __builtin_amdgcn_mfma_f32_16x16x32_bf16(af[mi], bfr[ni], acc[mi][ni], 0, 0, 0);
    }
    __syncthreads();   // all As reads complete before sb overwrites it

    // acc -> scan buffer (f32, pad 260)
    #pragma unroll
    for (int mi = 0; mi < 4; ++mi) {
        int row = mi * 16 + ((lane >> 4) << 2);
        #pragma unroll
        for (int ni = 0; ni < 4; ++ni) {
            int col = w * 64 + ni * 16 + (lane & 15);
            #pragma unroll
            for (int r = 0; r < 4; ++r)
                sb[(row + r) * 260 + col] = acc[mi][ni][r];
        }
    }
    __syncthreads();

    // local scan, 2-segment split: 256 threads (128 channels x 2 segs)
    {
        int ch = tid & 127, seg = tid >> 7;
        int pgl = (n0 >> 1) + ch;
        float2 a = ((const float2*)Abar)[pgl];
        float xr = 0.0f, xi = 0.0f;
        if (seg == 0) {
            unsigned int* xsp = xs + (size_t)m0 * 256 + pgl;
            #pragma unroll 8
            for (int r = 0; r < 32; ++r) {
                float2 bu = *(const float2*)&sb[r * 260 + 2 * ch];
                float nr  = fmaf(a.x, xr, fmaf(-a.y, xi, bu.x));
                float nim = fmaf(a.x, xi, fmaf(a.y, xr, bu.y));
                xr = nr; xi = nim;
                xsp[(size_t)r * 256] = cvtpk_bf16(xr, xi);
            }
            sEndv[ch] = make_float2(xr, xi);
        } else {
            #pragma unroll 8
            for (int r = 32; r < 64; ++r) {
                float2 bu = *(const float2*)&sb[r * 260 + 2 * ch];
                float nr  = fmaf(a.x, xr, fmaf(-a.y, xi, bu.x));
                float nim = fmaf(a.x, xi, fmaf(a.y, xr, bu.y));
                xr = nr; xi = nim;
                *(float2*)&sb[r * 260 + 2 * ch] = make_float2(xr, xi);
            }
        }
    }
    __syncthreads();
    if (tid >= 128) {
        int ch = tid & 127;
        int pgl = (n0 >> 1) + ch;
        float2 a = ((const float2*)Abar)[pgl];
        float2 I = sEndv[ch];
        float wr = a.x, wi = a.y;
        unsigned int* xsp = xs + (size_t)m0 * 256 + pgl;
        float xr = 0.0f, xi = 0.0f;
        #pragma unroll 8
        for (int r = 32; r < 64; ++r) {
            float2 y = *(const float2*)&sb[r * 260 + 2 * ch];
            xr = y.x + wr * I.x - wi * I.y;
            xi = y.y + wr * I.y + wi * I.x;
            xsp[(size_t)r * 256] = cvtpk_bf16(xr, xi);
            float tw = wr * a.x - wi * a.y;
            wi = wr * a.y + wi * a.x;
            wr = tw;
        }
        ((float2*)local_end)[(size_t)c * 256 + pgl] = make_float2(xr, xi);
    }
}

// ---------------------------------------------------------------------------
// scan2: carry scan over 512 chunks (r6-proven version, unchanged)
// ---------------------------------------------------------------------------
__global__ void s5_scan2(const float* __restrict__ local_end,
                         float* __restrict__ carry,
                         const float* __restrict__ powt,
                         float* __restrict__ out_state)
{
    int p = threadIdx.x;
    float2 A = ((const float2*)powt)[CHUNK * 256 + p];   // Abar^64
    float cr = 0.0f, ci = 0.0f;
    for (int cb = 0; cb < NCHUNK; cb += 16) {
        float2 e[16];
        #pragma unroll
        for (int j = 0; j < 16; ++j)
            e[j] = ((const float2*)local_end)[(size_t)(cb + j) * 256 + p];
        #pragma unroll
        for (int j = 0; j < 16; ++j) {
            ((float2*)carry)[(size_t)(cb + j) * 256 + p] = make_float2(cr, ci);
            float nr = fmaf(A.x, cr, fmaf(-A.y, ci, e[j].x));
            float ni = fmaf(A.x, ci, fmaf(A.y, cr, e[j].y));
            cr = nr; ci = ni;
        }
    }
    out_state[2 * p] = cr;
    out_state[2 * p + 1] = ci;
}

// ---------------------------------------------------------------------------
// k2: GEMM2 ys = fix(xs) @ W2 + D*u. 64x256 tile, K=512, BK=32, As dbuf with
// fixup during staging; B-fragments DIRECT from global fragment-major W2F.
// (r8-proven version, unchanged.) grid 512 x 256 thr.
// ---------------------------------------------------------------------------
__global__ __launch_bounds__(256) void s5_k2(const unsigned int* __restrict__ xs,
                                             const short* __restrict__ W2F,
                                             const float* __restrict__ carry,
                                             const float* __restrict__ powt,
                                             const float* __restrict__ Dv,
                                             const float* __restrict__ U,
                                             float* __restrict__ Out)
{
    __shared__ char smem[33280];
    short* As0 = (short*)smem;                    // [64][40] bf16, 5120 B
    short* As1 = (short*)(smem + 5120);           // [64][40]
    float* carryLds = (float*)(smem + 10240);     // 512 f32, 2048 B
    float* sb = (float*)smem;                     // [32][260] f32 epilogue (alias)

    const int tid = threadIdx.x, lane = tid & 63, w = tid >> 6;
    const int c  = blockIdx.x;
    const int m0 = c * 64;
    f32x4 acc[4][4] = {};

    const int arow = tid >> 2;
    const int akc  = (tid & 3) << 3;

    ((float2*)carryLds)[tid] = ((const float2*)carry)[(size_t)c * 256 + tid];
    __syncthreads();

    #define STAGE_A(S, AS)                                                        \
    {                                                                             \
        int k0_ = (S) * 32;                                                       \
        uint4 xv = *(const uint4*)&xs[(size_t)(m0 + arow) * 256 + ((k0_ + akc) >> 1)]; \
        const float4* pwp = (const float4*)&powt[(size_t)(arow + 1) * 512 + k0_ + akc]; \
        float4 p0 = pwp[0], p1 = pwp[1];                                          \
        float4 c0 = *(const float4*)&carryLds[k0_ + akc];                         \
        float4 c1 = *(const float4*)&carryLds[k0_ + akc + 4];                     \
        float r0 = bf2f(xv.x & 0xffffu), i0 = bf2f(xv.x >> 16);                   \
        float r1 = bf2f(xv.y & 0xffffu), i1 = bf2f(xv.y >> 16);                   \
        float r2 = bf2f(xv.z & 0xffffu), i2 = bf2f(xv.z >> 16);                   \
        float r3 = bf2f(xv.w & 0xffffu), i3 = bf2f(xv.w >> 16);                   \
        r0 += p0.x * c0.x - p0.y * c0.y;  i0 += p0.x * c0.y + p0.y * c0.x;        \
        r1 += p0.z * c0.z - p0.w * c0.w;  i1 += p0.z * c0.w + p0.w * c0.z;        \
        r2 += p1.x * c1.x - p1.y * c1.y;  i2 += p1.x * c1.y + p1.y * c1.x;        \
        r3 += p1.z * c1.z - p1.w * c1.w;  i3 += p1.z * c1.w + p1.w * c1.z;        \
        uint4 wv;                                                                 \
        wv.x = cvtpk_bf16(r0, i0); wv.y = cvtpk_bf16(r1, i1);                     \
        wv.z = cvtpk_bf16(r2, i2); wv.w = cvtpk_bf16(r3, i3);                     \
        *(uint4*)&(AS)[arow * 40 + akc] = wv;                                     \
    }

    #define COMPUTE(S, AS)                                                        \
    {                                                                             \
        short8 af[4], bfr[4];                                                     \
        _Pragma("unroll")                                                         \
        for (int mi = 0; mi < 4; ++mi)                                            \
            af[mi] = *(const short8*)&(AS)[(mi * 16 + (lane & 15)) * 40 + ((lane >> 4) << 3)]; \
        _Pragma("unroll")                                                         \
        for (int ni = 0; ni < 4; ++ni)                                            \
            bfr[ni] = *(const short8*)&W2F[(size_t)((S) * 16 + w * 4 + ni) * 512 + lane * 8]; \
        _Pragma("unroll")                                                         \
        for (int mi = 0; mi < 4; ++mi)                                            \
            _Pragma("unroll")                                                     \
            for (int ni = 0; ni < 4; ++ni)                                        \
                acc[mi][ni] = __builtin_amdgcn_mfma_f32_16x16x32_bf16(af[mi], bfr[ni], acc[mi][ni], 0, 0, 0); \
    }

    STAGE_A(0, As0);
    __syncthreads();

    for (int s = 0; s < 16; s += 2) {
        STAGE_A(s + 1, As1);
        COMPUTE(s, As0);
        __syncthreads();
        if (s + 2 < 16) STAGE_A(s + 2, As0);
        COMPUTE(s + 1, As1);
        __syncthreads();
    }

    // ---- epilogue: LDS transpose -> float4 stores (+ D*u) ----
    #pragma unroll
    for (int pass = 0; pass < 2; ++pass) {
        #pragma unroll
        for (int mi2 = 0; mi2 < 2; ++mi2) {
            int mi = pass * 2 + mi2;
            int lr0 = mi2 * 16 + ((lane >> 4) << 2);
            #pragma unroll
            for (int ni = 0; ni < 4; ++ni) {
                int col = w * 64 + ni * 16 + (lane & 15);
                #pragma unroll
                for (int r = 0; r < 4; ++r)
                    sb[(lr0 + r) * 260 + col] = acc[mi][ni][r];
            }
        }
        __syncthreads();
        #pragma unroll
        for (int j = 0; j < 8; ++j) {
            int idx = tid + j * 256;
            int lrow = idx >> 6, c4 = (idx & 63) << 2;
            int grow = m0 + pass * 32 + lrow;
            float4 v  = *(const float4*)&sb[lrow * 260 + c4];
            float4 uv = *(const float4*)&U[(size_t)grow * 256 + c4];
            float4 dv = *(const float4*)&Dv[c4];
            float4 o;
            o.x = v.x + dv.x * uv.x;
            o.y = v.y + dv.y * uv.y;
            o.z = v.z + dv.z * uv.z;
            o.w = v.w + dv.w * uv.w;
            *(float4*)&Out[(size_t)grow * 256 + c4] = o;
        }
        __syncthreads();
    }
    #undef STAGE_A
    #undef COMPUTE
}

// ---------------------------------------------------------------------------
extern "C" void kernel_launch(void* const* d_in, const int* in_sizes, int n_in,
                              void* d_out, int out_size, void* d_ws, size_t ws_size,
                              hipStream_t stream)
{
    const float* u        = (const float*)d_in[0];
    // d_in[1] = prev_state: provably never affects outputs (A_0 never enters
    // the associative-scan products; and it's zero anyway)
    const float* Lambda   = (const float*)d_in[2];
    const float* B        = (const float*)d_in[3];
    const float* C        = (const float*)d_in[4];
    const float* D        = (const float*)d_in[5];
    const float* log_step = (const float*)d_in[6];
    float* out = (float*)d_out;

    // workspace layout
    unsigned int* xs = (unsigned int*)d_ws;               // L*256 u32 (bf16 pairs) = 32 MB
    float* powt      = (float*)(xs + (size_t)LSEQ * 256); // 65*512
    float* Abar      = powt + 65 * 512;                   // 512
    float* local_end = Abar + 512;                        // 512*512
    float* carry     = local_end + (size_t)NCHUNK * 512;  // 512*512
    short* W1F       = (short*)(carry + (size_t)NCHUNK * 512); // 512*256
    short* W2F       = W1F + 512 * 256;                   // 256*512

    s5_prep<<<256, 256, 0, stream>>>(Lambda, log_step, B, C, Abar, powt, W1F, W2F);
    s5_k1<<<dim3(2, NCHUNK), 256, 0, stream>>>(u, W1F, Abar, xs, local_end);
    s5_scan2<<<1, 256, 0, stream>>>(local_end, carry, powt, out + (size_t)LSEQ * HDIM);
    s5_k2<<<NCHUNK, 256, 0, stream>>>(xs, W2F, carry, powt, D, u, out);
}

// Round 10
// 89.208 us; speedup vs baseline: 1.5117x; 1.0715x over previous
//
#include <hip/hip_runtime.h>

#define LSEQ 32768
#define HDIM 256
#define PDIM 256
#define CHUNK 64
#define NCHUNK 512   // LSEQ / CHUNK

typedef __attribute__((ext_vector_type(8))) short short8;
typedef __attribute__((ext_vector_type(4))) float f32x4;

static __device__ __forceinline__ unsigned short f2bf(float f) {
    unsigned int u = __float_as_uint(f);
    return (unsigned short)((u + 0x7FFFu + ((u >> 16) & 1u)) >> 16);
}
static __device__ __forceinline__ float bf2f(unsigned int lo16) {
    return __uint_as_float(lo16 << 16);
}
// packed f32x2 -> bf16x2 in one VALU op (low word = a, high word = b)
static __device__ __forceinline__ unsigned int cvtpk_bf16(float a, float b) {
    unsigned int r;
    asm("v_cvt_pk_bf16_f32 %0, %1, %2" : "=v"(r) : "v"(a), "v"(b));
    return r;
}

// fragment-major weight index: one frag = 64 lanes x 8 contiguous bf16 (=16B).
// element (n,k) of an [N][K] matrix stored as 16x16x32 MFMA B-fragments:
//   frag = (k>>5)*(N/16) + (n>>4);  lane = (n&15) + (((k>>3)&3)<<4);  e = k&7
// VALIDATED on-device (r8 k2, r9 k1).
static __device__ __forceinline__ size_t fragidx(int n, int k, int ntiles) {
    return ((size_t)((k >> 5) * ntiles + (n >> 4))) * 512 +
           (size_t)(((n & 15) + (((k >> 3) & 3) << 4)) * 8 + (k & 7));
}

// ---------------------------------------------------------------------------
// prep: grid 256 x 256 thr. (r9-proven, unchanged)
// ---------------------------------------------------------------------------
__global__ void s5_prep(const float* __restrict__ Lambda,
                        const float* __restrict__ log_step,
                        const float* __restrict__ B,
                        const float* __restrict__ C,
                        float* __restrict__ Abar,
                        float* __restrict__ powt,
                        short* __restrict__ W1F,
                        short* __restrict__ W2F)
{
    const int b = blockIdx.x, t = threadIdx.x;

    {   // discretization for p = t
        float lr = Lambda[2 * t], li = Lambda[2 * t + 1];
        float step = expf(log_step[t]);
        float s2 = 0.5f * step;
        float dr = 1.0f - s2 * lr, di = -s2 * li;
        float inv = 1.0f / (dr * dr + di * di);
        float blr = dr * inv, bli = -di * inv;
        float nr = 1.0f + s2 * lr, ni = s2 * li;
        float ar = blr * nr - bli * ni;
        float ai = blr * ni + bli * nr;

        if (b <= 64) {   // powt[b][t] = (ar,ai)^b, iterative
            float pr = 1.0f, pi = 0.0f;
            for (int k = 0; k < b; ++k) {
                float tr = pr * ar - pi * ai;
                pi = pr * ai + pi * ar;
                pr = tr;
            }
            powt[(size_t)b * 512 + 2 * t] = pr;
            powt[(size_t)b * 512 + 2 * t + 1] = pi;
        }
        if (b == 1) { Abar[2 * t] = ar; Abar[2 * t + 1] = ai; }
    }
    {   // W1F rows for p = b (fragment-major, N=512 -> ntiles=32, K=256)
        float lr = Lambda[2 * b], li = Lambda[2 * b + 1];
        float step = expf(log_step[b]);
        float s2 = 0.5f * step;
        float dr = 1.0f - s2 * lr, di = -s2 * li;
        float inv = 1.0f / (dr * dr + di * di);
        float gr = dr * inv * step, gi = -di * inv * step;
        float br = B[(size_t)(b * HDIM + t) * 2];
        float bi = B[(size_t)(b * HDIM + t) * 2 + 1];
        W1F[fragidx(2 * b,     t, 32)] = (short)f2bf(gr * br - gi * bi);
        W1F[fragidx(2 * b + 1, t, 32)] = (short)f2bf(gr * bi + gi * br);
    }
    {   // W2F row h = b (fragment-major, N=256 -> ntiles=16, K=512)
        float cr = C[(size_t)(b * PDIM + t) * 2];
        float ci = C[(size_t)(b * PDIM + t) * 2 + 1];
        W2F[fragidx(b, 2 * t,     16)] = (short)f2bf(cr);
        W2F[fragidx(b, 2 * t + 1, 16)] = (short)f2bf(-ci);
    }
}

// ---------------------------------------------------------------------------
// k1: ONE block per chunk (full N=512), 512 thr / 8 waves (2m x 4n).
// u staged ONCE (was twice). Barrier-free GEMM, W1F direct (r9-validated).
// Per N-half: acc -> sb f32 -> proven 2-segment scan -> xs bf16 + local_end.
// ---------------------------------------------------------------------------
__global__ __launch_bounds__(512, 4) void s5_k1(const float* __restrict__ U,
                                                const short* __restrict__ W1F,
                                                const float* __restrict__ Abar,
                                                unsigned int* __restrict__ xs,
                                                float* __restrict__ local_end)
{
    __shared__ char smem[67584];
    short* As = (short*)smem;             // [64][264] bf16 (pad +8), 33792 B
    float* sb = (float*)smem;             // [64][260] f32 aliased after GEMM (66560 B)
    float2* sEndv = (float2*)(smem + 66560);  // [128]

    const int tid = threadIdx.x;
    const int lane = tid & 63, w = tid >> 6;
    const int wm = w >> 2, wn = w & 3;
    const int c  = blockIdx.x;
    const int m0 = c * CHUNK;

    // stage u tile -> bf16 (once per chunk)
    #pragma unroll
    for (int i = 0; i < 4; ++i) {
        int gidx = tid + i * 512;
        int row = gidx >> 5, kc = (gidx & 31) << 3;
        const float4* up = (const float4*)&U[(size_t)(m0 + row) * 256 + kc];
        float4 v0 = up[0], v1 = up[1];
        uint4 wv;
        wv.x = cvtpk_bf16(v0.x, v0.y);
        wv.y = cvtpk_bf16(v0.z, v0.w);
        wv.z = cvtpk_bf16(v1.x, v1.y);
        wv.w = cvtpk_bf16(v1.z, v1.w);
        *(uint4*)&As[row * 264 + kc] = wv;
    }
    __syncthreads();

    f32x4 acc[2][2][4] = {};   // [mi][half][ni]

    // barrier-free K-loop: A frags from LDS, B frags direct from W1F (L2)
    for (int s = 0; s < 8; ++s) {
        int k0 = s * 32;
        short8 af[2];
        #pragma unroll
        for (int mi = 0; mi < 2; ++mi)
            af[mi] = *(const short8*)&As[(wm * 32 + mi * 16 + (lane & 15)) * 264 + k0 + ((lane >> 4) << 3)];
        #pragma unroll
        for (int half = 0; half < 2; ++half) {
            short8 bfr[4];
            #pragma unroll
            for (int ni = 0; ni < 4; ++ni)
                bfr[ni] = *(const short8*)&W1F[(size_t)(s * 32 + half * 16 + wn * 4 + ni) * 512 + lane * 8];
            #pragma unroll
            for (int mi = 0; mi < 2; ++mi)
                #pragma unroll
                for (int ni = 0; ni < 4; ++ni)
                    acc[mi][half][ni] = __builtin_amdgcn_mfma_f32_16x16x32_bf16(af[mi], bfr[ni], acc[mi][half][ni], 0, 0, 0);
        }
    }
    __syncthreads();   // all As reads complete before sb overwrites it

    for (int half = 0; half < 2; ++half) {
        // acc -> scan buffer (f32, pad 260)
        #pragma unroll
        for (int mi = 0; mi < 2; ++mi) {
            int row = wm * 32 + mi * 16 + ((lane >> 4) << 2);
            #pragma unroll
            for (int ni = 0; ni < 4; ++ni) {
                int col = wn * 64 + ni * 16 + (lane & 15);
                #pragma unroll
                for (int r = 0; r < 4; ++r)
                    sb[(row + r) * 260 + col] = acc[mi][half][ni][r];
            }
        }
        __syncthreads();

        // local scan, 2-segment split (r9-proven): threads 0..255 active
        if (tid < 256) {
            int ch = tid & 127, seg = tid >> 7;
            int pgl = half * 128 + ch;
            float2 a = ((const float2*)Abar)[pgl];
            float xr = 0.0f, xi = 0.0f;
            if (seg == 0) {
                unsigned int* xsp = xs + (size_t)m0 * 256 + pgl;
                #pragma unroll 8
                for (int r = 0; r < 32; ++r) {
                    float2 bu = *(const float2*)&sb[r * 260 + 2 * ch];
                    float nr  = fmaf(a.x, xr, fmaf(-a.y, xi, bu.x));
                    float nim = fmaf(a.x, xi, fmaf(a.y, xr, bu.y));
                    xr = nr; xi = nim;
                    xsp[(size_t)r * 256] = cvtpk_bf16(xr, xi);
                }
                sEndv[ch] = make_float2(xr, xi);
            } else {
                #pragma unroll 8
                for (int r = 32; r < 64; ++r) {
                    float2 bu = *(const float2*)&sb[r * 260 + 2 * ch];
                    float nr  = fmaf(a.x, xr, fmaf(-a.y, xi, bu.x));
                    float nim = fmaf(a.x, xi, fmaf(a.y, xr, bu.y));
                    xr = nr; xi = nim;
                    *(float2*)&sb[r * 260 + 2 * ch] = make_float2(xr, xi);
                }
            }
        }
        __syncthreads();
        if (tid >= 128 && tid < 256) {
            int ch = tid & 127;
            int pgl = half * 128 + ch;
            float2 a = ((const float2*)Abar)[pgl];
            float2 I = sEndv[ch];
            float wr = a.x, wi = a.y;
            unsigned int* xsp = xs + (size_t)m0 * 256 + pgl;
            float xr = 0.0f, xi = 0.0f;
            #pragma unroll 8
            for (int r = 32; r < 64; ++r) {
                float2 y = *(const float2*)&sb[r * 260 + 2 * ch];
                xr = y.x + wr * I.x - wi * I.y;
                xi = y.y + wr * I.y + wi * I.x;
                xsp[(size_t)r * 256] = cvtpk_bf16(xr, xi);
                float tw = wr * a.x - wi * a.y;
                wi = wr * a.y + wi * a.x;
                wr = tw;
            }
            ((float2*)local_end)[(size_t)c * 256 + pgl] = make_float2(xr, xi);
        }
        __syncthreads();   // sb/sEndv dead before next half overwrites
    }
}

// ---------------------------------------------------------------------------
// scan2: carry scan over 512 chunks (r6-proven version, unchanged)
// ---------------------------------------------------------------------------
__global__ void s5_scan2(const float* __restrict__ local_end,
                         float* __restrict__ carry,
                         const float* __restrict__ powt,
                         float* __restrict__ out_state)
{
    int p = threadIdx.x;
    float2 A = ((const float2*)powt)[CHUNK * 256 + p];   // Abar^64
    float cr = 0.0f, ci = 0.0f;
    for (int cb = 0; cb < NCHUNK; cb += 16) {
        float2 e[16];
        #pragma unroll
        for (int j = 0; j < 16; ++j)
            e[j] = ((const float2*)local_end)[(size_t)(cb + j) * 256 + p];
        #pragma unroll
        for (int j = 0; j < 16; ++j) {
            ((float2*)carry)[(size_t)(cb + j) * 256 + p] = make_float2(cr, ci);
            float nr = fmaf(A.x, cr, fmaf(-A.y, ci, e[j].x));
            float ni = fmaf(A.x, ci, fmaf(A.y, cr, e[j].y));
            cr = nr; ci = ni;
        }
    }
    out_state[2 * p] = cr;
    out_state[2 * p + 1] = ci;
}

// ---------------------------------------------------------------------------
// k2: GEMM2 ys = fix(xs) @ W2 + D*u. (r8-proven version, unchanged.)
// ---------------------------------------------------------------------------
__global__ __launch_bounds__(256) void s5_k2(const unsigned int* __restrict__ xs,
                                             const short* __restrict__ W2F,
                                             const float* __restrict__ carry,
                                             const float* __restrict__ powt,
                                             const float* __restrict__ Dv,
                                             const float* __restrict__ U,
                                             float* __restrict__ Out)
{
    __shared__ char smem[33280];
    short* As0 = (short*)smem;                    // [64][40] bf16, 5120 B
    short* As1 = (short*)(smem + 5120);           // [64][40]
    float* carryLds = (float*)(smem + 10240);     // 512 f32, 2048 B
    float* sb = (float*)smem;                     // [32][260] f32 epilogue (alias)

    const int tid = threadIdx.x, lane = tid & 63, w = tid >> 6;
    const int c  = blockIdx.x;
    const int m0 = c * 64;
    f32x4 acc[4][4] = {};

    const int arow = tid >> 2;
    const int akc  = (tid & 3) << 3;

    ((float2*)carryLds)[tid] = ((const float2*)carry)[(size_t)c * 256 + tid];
    __syncthreads();

    #define STAGE_A(S, AS)                                                        \
    {                                                                             \
        int k0_ = (S) * 32;                                                       \
        uint4 xv = *(const uint4*)&xs[(size_t)(m0 + arow) * 256 + ((k0_ + akc) >> 1)]; \
        const float4* pwp = (const float4*)&powt[(size_t)(arow + 1) * 512 + k0_ + akc]; \
        float4 p0 = pwp[0], p1 = pwp[1];                                          \
        float4 c0 = *(const float4*)&carryLds[k0_ + akc];                         \
        float4 c1 = *(const float4*)&carryLds[k0_ + akc + 4];                     \
        float r0 = bf2f(xv.x & 0xffffu), i0 = bf2f(xv.x >> 16);                   \
        float r1 = bf2f(xv.y & 0xffffu), i1 = bf2f(xv.y >> 16);                   \
        float r2 = bf2f(xv.z & 0xffffu), i2 = bf2f(xv.z >> 16);                   \
        float r3 = bf2f(xv.w & 0xffffu), i3 = bf2f(xv.w >> 16);                   \
        r0 += p0.x * c0.x - p0.y * c0.y;  i0 += p0.x * c0.y + p0.y * c0.x;        \
        r1 += p0.z * c0.z - p0.w * c0.w;  i1 += p0.z * c0.w + p0.w * c0.z;        \
        r2 += p1.x * c1.x - p1.y * c1.y;  i2 += p1.x * c1.y + p1.y * c1.x;        \
        r3 += p1.z * c1.z - p1.w * c1.w;  i3 += p1.z * c1.w + p1.w * c1.z;        \
        uint4 wv;                                                                 \
        wv.x = cvtpk_bf16(r0, i0); wv.y = cvtpk_bf16(r1, i1);                     \
        wv.z = cvtpk_bf16(r2, i2); wv.w = cvtpk_bf16(r3, i3);                     \
        *(uint4*)&(AS)[arow * 40 + akc] = wv;                                     \
    }

    #define COMPUTE(S, AS)                                                        \
    {                                                                             \
        short8 af[4], bfr[4];                                                     \
        _Pragma("unroll")                                                         \
        for (int mi = 0; mi < 4; ++mi)                                            \
            af[mi] = *(const short8*)&(AS)[(mi * 16 + (lane & 15)) * 40 + ((lane >> 4) << 3)]; \
        _Pragma("unroll")                                                         \
        for (int ni = 0; ni < 4; ++ni)                                            \
            bfr[ni] = *(const short8*)&W2F[(size_t)((S) * 16 + w * 4 + ni) * 512 + lane * 8]; \
        _Pragma("unroll")                                                         \
        for (int mi = 0; mi < 4; ++mi)                                            \
            _Pragma("unroll")                                                     \
            for (int ni = 0; ni < 4; ++ni)                                        \
                acc[mi][ni] = __builtin_amdgcn_mfma_f32_16x16x32_bf16(af[mi], bfr[ni], acc[mi][ni], 0, 0, 0); \
    }

    STAGE_A(0, As0);
    __syncthreads();

    for (int s = 0; s < 16; s += 2) {
        STAGE_A(s + 1, As1);
        COMPUTE(s, As0);
        __syncthreads();
        if (s + 2 < 16) STAGE_A(s + 2, As0);
        COMPUTE(s + 1, As1);
        __syncthreads();
    }

    // ---- epilogue: LDS transpose -> float4 stores (+ D*u) ----
    #pragma unroll
    for (int pass = 0; pass < 2; ++pass) {
        #pragma unroll
        for (int mi2 = 0; mi2 < 2; ++mi2) {
            int mi = pass * 2 + mi2;
            int lr0 = mi2 * 16 + ((lane >> 4) << 2);
            #pragma unroll
            for (int ni = 0; ni < 4; ++ni) {
                int col = w * 64 + ni * 16 + (lane & 15);
                #pragma unroll
                for (int r = 0; r < 4; ++r)
                    sb[(lr0 + r) * 260 + col] = acc[mi][ni][r];
            }
        }
        __syncthreads();
        #pragma unroll
        for (int j = 0; j < 8; ++j) {
            int idx = tid + j * 256;
            int lrow = idx >> 6, c4 = (idx & 63) << 2;
            int grow = m0 + pass * 32 + lrow;
            float4 v  = *(const float4*)&sb[lrow * 260 + c4];
            float4 uv = *(const float4*)&U[(size_t)grow * 256 + c4];
            float4 dv = *(const float4*)&Dv[c4];
            float4 o;
            o.x = v.x + dv.x * uv.x;
            o.y = v.y + dv.y * uv.y;
            o.z = v.z + dv.z * uv.z;
            o.w = v.w + dv.w * uv.w;
            *(float4*)&Out[(size_t)grow * 256 + c4] = o;
        }
        __syncthreads();
    }
    #undef STAGE_A
    #undef COMPUTE
}

// ---------------------------------------------------------------------------
extern "C" void kernel_launch(void* const* d_in, const int* in_sizes, int n_in,
                              void* d_out, int out_size, void* d_ws, size_t ws_size,
                              hipStream_t stream)
{
    const float* u        = (const float*)d_in[0];
    // d_in[1] = prev_state: provably never affects outputs (A_0 never enters
    // the associative-scan products; and it's zero anyway)
    const float* Lambda   = (const float*)d_in[2];
    const float* B        = (const float*)d_in[3];
    const float* C        = (const float*)d_in[4];
    const float* D        = (const float*)d_in[5];
    const float* log_step = (const float*)d_in[6];
    float* out = (float*)d_out;

    // workspace layout
    unsigned int* xs = (unsigned int*)d_ws;               // L*256 u32 (bf16 pairs) = 32 MB
    float* powt      = (float*)(xs + (size_t)LSEQ * 256); // 65*512
    float* Abar      = powt + 65 * 512;                   // 512
    float* local_end = Abar + 512;                        // 512*512
    float* carry     = local_end + (size_t)NCHUNK * 512;  // 512*512
    short* W1F       = (short*)(carry + (size_t)NCHUNK * 512); // 512*256
    short* W2F       = W1F + 512 * 256;                   // 256*512

    s5_prep<<<256, 256, 0, stream>>>(Lambda, log_step, B, C, Abar, powt, W1F, W2F);
    s5_k1<<<NCHUNK, 512, 0, stream>>>(u, W1F, Abar, xs, local_end);
    s5_scan2<<<1, 256, 0, stream>>>(local_end, carry, powt, out + (size_t)LSEQ * HDIM);
    s5_k2<<<NCHUNK, 256, 0, stream>>>(xs, W2F, carry, powt, D, u, out);
}